// Round 17
// baseline (1326.147 us; speedup 1.0000x reference)
//
#include <hip/hip_runtime.h>
#include <stdint.h>

#define H 256
#define PIX (H*H)
#define BATCH 2
#define NV 5023
#define NF 9976
#define EPS 1e-5f
#define NTILE 256          // 16x16-px binning tiles
#define CH 256
#define NSEG 64
#define NBINS (BATCH*NTILE*NSEG)
#define ZSPLIT 4

typedef unsigned long long ull;
#define INF_KEY 0x7F800000FFFFFFFFULL

__device__ __forceinline__ float axf(int i) {
    return 1.0f - (2.0f * (float)i + 1.0f) / (float)H;   // exact
}

__device__ __forceinline__ float bf16snap(float x) {     // round-to-nearest-even bf16
    unsigned u = __float_as_uint(x);
    unsigned r = (u + 0x7FFFu + ((u >> 16) & 1u)) & 0xFFFF0000u;
    return __uint_as_float(r);
}

__device__ __forceinline__ int zseg_of(float z) {
    int q = (int)floorf((z - 1.6f) * 80.0f);             // 64 segs over [1.6, 2.4]
    return q < 0 ? 0 : (q > 63 ? 63 : q);
}
__device__ __forceinline__ float zseg_lower(int s) {
    return (s == 0) ? 0.0f : 1.6f + (float)s * 0.0125f;  // certified lower bound
}

__device__ __forceinline__ bool tile_range_f(float xmn, float xmx, float ymn, float ymx,
                                             int& tx0, int& tx1, int& ty0, int& ty1) {
    int cx0 = (int)floorf(127.5f - 128.0f * xmx) - 1;
    int cx1 = (int)ceilf (127.5f - 128.0f * xmn) + 1;
    int cy0 = (int)floorf(127.5f - 128.0f * ymx) - 1;
    int cy1 = (int)ceilf (127.5f - 128.0f * ymn) + 1;
    cx0 = max(cx0, 0); cx1 = min(cx1, 255);
    cy0 = max(cy0, 0); cy1 = min(cy1, 255);
    if (cx0 > cx1 || cy0 > cy1) return false;
    tx0 = cx0 >> 4; tx1 = cx1 >> 4;
    ty0 = cy0 >> 4; ty1 = cy1 >> 4;
    return true;
}

// fd layout (slot permutation; all VALUES byte-identical to r11-r16):
// o[0..3] edge terms | o[4] x2 | o[5] y2 | o[6] den | o[7] okS
// o[8..11] xmn,xmx,ymn,ymx (bbox float4) | o[12..14] z0,z1,z2 | o[15] 0
__global__ void setup_all(const float* __restrict__ verts, const float* __restrict__ tm,
                          const float* __restrict__ focal, const int* __restrict__ faces,
                          float* __restrict__ fd, int* __restrict__ segArr,
                          float* __restrict__ vn, int* __restrict__ hist) {
#pragma clang fp contract(off)
    int t = blockIdx.x * blockDim.x + threadIdx.x;
    if (t >= BATCH * NF) return;
    int b = t / NF, f = t % NF;
    const float* M = tm + b * 12;
    float fl = focal[b];
    float X[3], Y[3], Z[3];
#pragma unroll
    for (int k = 0; k < 3; k++) {
        int vi = faces[f * 3 + k];
        const float* v = verts + (b * NV + vi) * 3;
        float v0 = v[0], v1 = v[1], v2 = v[2];
        float c0 = ((v0 * M[0] + v1 * M[4]) + v2 * M[8])  + M[3];
        float c1 = ((v0 * M[1] + v1 * M[5]) + v2 * M[9])  + M[7];
        float c2 = ((v0 * M[2] + v1 * M[6]) + v2 * M[10]) + M[11];
        X[k] = (fl * c0) / c2;
        Y[k] = (fl * c1) / c2;
        Z[k] = c2;
    }
    float x0 = X[0], x1 = X[1], x2 = X[2];
    float y0 = Y[0], y1 = Y[1], y2 = Y[2];
    float z0 = Z[0], z1 = Z[1], z2 = Z[2];
    float den = (y1 - y2) * (x0 - x2) + (x2 - x1) * (y0 - y2);
    bool zv = (z0 > EPS) && (z1 > EPS) && (z2 > EPS);
    bool okS = zv && (fabsf(den) > 1e-8f);
    bool okR = zv && (fabsf(den) > 5e-9f);
    float xmn, xmx, ymn, ymx;
    if (okR) {
        float e01 = (x1 - x0) * (x1 - x0) + (y1 - y0) * (y1 - y0);
        float e12 = (x2 - x1) * (x2 - x1) + (y2 - y1) * (y2 - y1);
        float e20 = (x0 - x2) * (x0 - x2) + (y0 - y2) * (y0 - y2);
        float E2 = fmaxf(fmaxf(e01, e12), e20);
        float delta = 1e-4f * E2 / fabsf(den) + 1e-3f;
        if (!(delta < 4.0f)) delta = 4.0f;
        xmn = fminf(fminf(x0, x1), x2) - delta;
        xmx = fmaxf(fmaxf(x0, x1), x2) + delta;
        ymn = fminf(fminf(y0, y1), y2) - delta;
        ymx = fmaxf(fmaxf(y0, y1), y2) + delta;
    } else {
        xmn = 1e30f; xmx = -1e30f; ymn = 1e30f; ymx = -1e30f;
    }
    float* o = fd + (size_t)t * 16;
    o[0] = y1 - y2;  o[1] = x2 - x1;
    o[2] = y2 - y0;  o[3] = x0 - x2;
    o[4] = x2;       o[5] = y2;
    o[6] = den;      o[7] = okS ? 1.0f : 0.0f;
    o[8] = xmn;  o[9] = xmx;  o[10] = ymn;  o[11] = ymx;
    o[12] = z0;  o[13] = z1;  o[14] = z2;   o[15] = 0.0f;
    int seg = -1;
    if (okR) seg = zseg_of(fminf(fminf(z0, z1), z2));
    segArr[t] = seg;

    // face-normal scatter (same math as r11-r16)
    {
        int i0 = faces[f*3+0], i1 = faces[f*3+1], i2 = faces[f*3+2];
        const float* vb = verts + b * NV * 3;
        float a0 = vb[i0*3+0], a1 = vb[i0*3+1], a2 = vb[i0*3+2];
        float b0 = vb[i1*3+0], b1 = vb[i1*3+1], b2 = vb[i1*3+2];
        float c0 = vb[i2*3+0], c1 = vb[i2*3+1], c2 = vb[i2*3+2];
        float e1x = b0 - a0, e1y = b1 - a1, e1z = b2 - a2;
        float e2x = c0 - a0, e2y = c1 - a1, e2z = c2 - a2;
        float nx = e1y * e2z - e1z * e2y;
        float ny = e1z * e2x - e1x * e2z;
        float nz = e1x * e2y - e1y * e2x;
        float* nb = vn + (size_t)b * NV * 3;
        atomicAdd(&nb[i0*3+0], nx); atomicAdd(&nb[i0*3+1], ny); atomicAdd(&nb[i0*3+2], nz);
        atomicAdd(&nb[i1*3+0], nx); atomicAdd(&nb[i1*3+1], ny); atomicAdd(&nb[i1*3+2], nz);
        atomicAdd(&nb[i2*3+0], nx); atomicAdd(&nb[i2*3+1], ny); atomicAdd(&nb[i2*3+2], nz);
    }

    if (seg >= 0) {
        int tx0, tx1, ty0, ty1;
        if (tile_range_f(xmn, xmx, ymn, ymx, tx0, tx1, ty0, ty1)) {
            for (int ty = ty0; ty <= ty1; ty++)
                for (int tx = tx0; tx <= tx1; tx++)
                    atomicAdd(&hist[((b * NTILE) + (ty * 16 + tx)) * NSEG + seg], 1);
        }
    }
}

__global__ __launch_bounds__(1024) void bin_scan(const int* __restrict__ hist,
                                                 int* __restrict__ start) {
    __shared__ int tot[1024];
    int t = threadIdx.x;
    int base = t * (NBINS / 1024);
    int loc[NBINS / 1024];
    int s = 0;
#pragma unroll
    for (int i = 0; i < NBINS / 1024; i++) { loc[i] = s; s += hist[base + i]; }
    tot[t] = s;
    __syncthreads();
    for (int off = 1; off < 1024; off <<= 1) {
        int x = tot[t];
        if (t >= off) x += tot[t - off];
        __syncthreads();
        tot[t] = x;
        __syncthreads();
    }
    int pre = (t > 0) ? tot[t - 1] : 0;
#pragma unroll
    for (int i = 0; i < NBINS / 1024; i++) start[base + i] = pre + loc[i];
    if (t == 1023) start[NBINS] = tot[1023];
}

// bin scatter + (fused) vertex-normal normalize
__global__ void bin_scatter(const float* __restrict__ fd, const int* __restrict__ segArr,
                            const int* __restrict__ start, int* __restrict__ cursor,
                            int* __restrict__ list, int cap, float* __restrict__ vn) {
#pragma clang fp contract(off)
    int t = blockIdx.x * blockDim.x + threadIdx.x;
    if (t < BATCH * NV) {
        float x = vn[t*3+0], y = vn[t*3+1], z = vn[t*3+2];
        float n = fmaxf(sqrtf((x*x + y*y) + z*z), 1e-6f);
        vn[t*3+0] = x / n; vn[t*3+1] = y / n; vn[t*3+2] = z / n;
    }
    if (t >= BATCH * NF) return;
    int seg = segArr[t];
    if (seg < 0) return;
    int b = t / NF, f = t % NF;
    const float* o = fd + (size_t)t * 16;
    int tx0, tx1, ty0, ty1;
    if (!tile_range_f(o[8], o[9], o[10], o[11], tx0, tx1, ty0, ty1)) return;
    int entry = (seg << 14) | f;            // NF < 2^14, seg < 2^6
    for (int ty = ty0; ty <= ty1; ty++)
        for (int tx = tx0; tx <= tx1; tx++) {
            int bin = ((b * NTILE) + (ty * 16 + tx)) * NSEG + seg;
            int dst = start[bin] + atomicAdd(&cursor[bin], 1);
            if (dst < cap) list[dst] = entry;
        }
}

// z-sliced binned raster: block (tile, b, s) scans the s-th quarter of the
// tile's seg-sorted list. Per-slice key top-2 + frozen certified break
// (skipped faces can't enter the local top-2); global winner via merge.
__global__ __launch_bounds__(256) void raster(const float* __restrict__ fd,
                                              const int* __restrict__ start,
                                              const int* __restrict__ list,
                                              ull* __restrict__ keyS,
                                              ull* __restrict__ keyA,
                                              ull* __restrict__ keyB) {
#pragma clang fp contract(off)
    __shared__ __align__(16) float sfd[CH * 16];
    __shared__ int sid[CH];
    int tid = threadIdx.x;
    int bz = blockIdx.z;
    int b = bz / ZSPLIT, s = bz % ZSPLIT;
    int tile = blockIdx.y * 16 + blockIdx.x;
    int tx = tid & 15, ty = tid >> 4;
    int col = blockIdx.x * 16 + tx, row = blockIdx.y * 16 + ty;
    float px = axf(col), py = axf(row);
    ull ks = INF_KEY, k1 = INF_KEY, k2 = INF_KEY;
    const float4* fdb4 = (const float4*)(fd + (size_t)b * NF * 16);
    int binbase = (b * NTILE + tile) * NSEG;
    int lbeg = start[binbase], lend = start[binbase + NSEG];
    long long L = (long long)(lend - lbeg);
    int sb = lbeg + (int)((L * s) / ZSPLIT);
    int se = lbeg + (int)((L * (s + 1)) / ZSPLIT);

    for (int fbase = sb; fbase < se; fbase += CH) {
        int n = min(CH, se - fbase);
        for (int j = tid; j < n; j += 256) sid[j] = list[fbase + j] & 0x3FFF;
        __syncthreads();
        for (int j = tid; j < n * 4; j += 256) {
            int e = sid[j >> 2];
            float4 v = fdb4[(size_t)e * 4 + (j & 3)];
            if ((j & 3) == 3) v.w = __uint_as_float((unsigned)e);  // face id in o[15]
            ((float4*)sfd)[j] = v;
        }
        __syncthreads();
        for (int i = 0; i < n; i++) {
            const float* o = sfd + i * 16;
            bool cand = (px >= o[8]) & (px <= o[9]) & (py >= o[10]) & (py <= o[11]);
            if (__ballot(cand) == 0ULL) continue;
            float dx = px - o[4], dy = py - o[5];
            float w0 = (o[0] * dx + o[1] * dy) / o[6];
            float w1 = (o[2] * dx + o[3] * dy) / o[6];
            float w2 = (1.0f - w0) - w1;
            bool insS = cand && (o[7] != 0.0f) && (w0 >= 0.0f) && (w1 >= 0.0f) && (w2 >= 0.0f);
            bool insR = cand && (w0 >= -1e-5f) && (w1 >= -1e-5f) && (w2 >= -1e-5f);
            if (__ballot(insR) == 0ULL) continue;
            float iz = ((w0 / o[12]) + (w1 / o[13])) + (w2 / o[14]);
            if (insR && (iz > 1e-8f)) {
                float zp = 1.0f / iz;
                ull key = ((ull)__float_as_uint(zp) << 32) |
                          (ull)(unsigned)__float_as_uint(o[15]);
                if (insS && key < ks) ks = key;
                if (key < k1) { k2 = k1; k1 = key; }
                else if (key < k2) { k2 = key; }
            }
        }
        // certified early break within slice (frozen inequality)
        if (fbase + CH < se) {
            float nf = zseg_lower(list[fbase + CH] >> 14);
            float madj = nf * (1.0f - 1e-4f);
            float zsv = __uint_as_float((unsigned)(ks >> 32));
            float zbv = __uint_as_float((unsigned)(k2 >> 32));
            bool done = (nf > 0.0f) && (ks != INF_KEY) && (k2 != INF_KEY) &&
                        (zsv < madj) && (zbv < madj);
            int notdone = __syncthreads_count(done ? 0 : 1);
            if (notdone == 0) break;
        } else {
            __syncthreads();
        }
    }
    size_t slot = ((size_t)bz) * PIX + (size_t)row * H + col;
    keyS[slot] = ks;
    keyA[slot] = k1;
    keyB[slot] = k2;
}

// merge slices -> (fs, fr); identical semantics to r12's merge
__global__ void merge(const ull* __restrict__ keyS, const ull* __restrict__ keyA,
                      const ull* __restrict__ keyB, int2* __restrict__ pix) {
    int t = blockIdx.x * blockDim.x + threadIdx.x;
    if (t >= BATCH * PIX) return;
    int b = t / PIX, p = t % PIX;
    ull mS = INF_KEY;
    for (int s = 0; s < ZSPLIT; s++) {
        ull k = keyS[((size_t)(b * ZSPLIT + s)) * PIX + p];
        if (k < mS) mS = k;
    }
    int fs = -1;
    float zs = 0.0f;
    if ((unsigned)(mS >> 32) != 0x7F800000u) {
        fs = (int)(unsigned)mS;
        zs = __uint_as_float((unsigned)(mS >> 32));
    }
    int fr = -1;
    if (fs >= 0) {
        ull mR = INF_KEY;
        for (int s = 0; s < ZSPLIT; s++) {
            size_t sl = ((size_t)(b * ZSPLIT + s)) * PIX + p;
            ull ka = keyA[sl];
            if ((int)(unsigned)ka != fs && ka < mR) mR = ka;
            ull kb = keyB[sl];
            if ((int)(unsigned)kb != fs && kb < mR) mR = kb;
        }
        if ((unsigned)(mR >> 32) != 0x7F800000u) {
            float zr = __uint_as_float((unsigned)(mR >> 32));
            if (fabsf(zr - zs) <= 0.05f * zs) fr = (int)(unsigned)mR;
        }
    }
    pix[t] = make_int2(fs, fr);
}

// faithful f32 shading (identical values to r11-r16; fd slots remapped)
__device__ void shade_face(int f, int b, float px, float py,
                           const float* __restrict__ fd, const float* __restrict__ verts,
                           const int* __restrict__ faces, const float* __restrict__ vn,
                           const float* __restrict__ tm, float* rgb) {
#pragma clang fp contract(off)
    const float* o = fd + ((size_t)b * NF + f) * 16;
    float dx = px - o[4], dy = py - o[5];
    float w0 = (o[0] * dx + o[1] * dy) / o[6];
    float w1 = (o[2] * dx + o[3] * dy) / o[6];
    float w2 = (1.0f - w0) - w1;
    float q0 = w0 / o[12], q1 = w1 / o[13], q2 = w2 / o[14];
    float iz = (q0 + q1) + q2;
    float zsafe = 1.0f / iz;
    float bw0 = q0 * zsafe, bw1 = q1 * zsafe, bw2 = q2 * zsafe;
    int i0 = faces[f*3+0], i1 = faces[f*3+1], i2 = faces[f*3+2];
    const float* vb = verts + b * NV * 3;
    const float* nb = vn + b * NV * 3;
    float posx = (bw0*vb[i0*3+0] + bw1*vb[i1*3+0]) + bw2*vb[i2*3+0];
    float posy = (bw0*vb[i0*3+1] + bw1*vb[i1*3+1]) + bw2*vb[i2*3+1];
    float posz = (bw0*vb[i0*3+2] + bw1*vb[i1*3+2]) + bw2*vb[i2*3+2];
    float nx = (bw0*nb[i0*3+0] + bw1*nb[i1*3+0]) + bw2*nb[i2*3+0];
    float ny = (bw0*nb[i0*3+1] + bw1*nb[i1*3+1]) + bw2*nb[i2*3+1];
    float nz = (bw0*nb[i0*3+2] + bw1*nb[i1*3+2]) + bw2*nb[i2*3+2];
    float nn = fmaxf(sqrtf((nx*nx + ny*ny) + nz*nz), 1e-6f);
    nx /= nn; ny /= nn; nz /= nn;
    const float* M = tm + b * 12;
    float T0 = M[3], T1 = M[7], T2 = M[11];
    float cpx = -((T0*M[0] + T1*M[1]) + T2*M[2]);
    float cpy = -((T0*M[4] + T1*M[5]) + T2*M[6]);
    float cpz = -((T0*M[8] + T1*M[9]) + T2*M[10]);
    float lx = 0.0f - posx, ly = 1.0f - posy, lz = 3.0f - posz;
    float ln = fmaxf(sqrtf((lx*lx + ly*ly) + lz*lz), 1e-6f);
    lx /= ln; ly /= ln; lz /= ln;
    float vx = cpx - posx, vy = cpy - posy, vz = cpz - posz;
    float vnn = fmaxf(sqrtf((vx*vx + vy*vy) + vz*vz), 1e-6f);
    vx /= vnn; vy /= vnn; vz /= vnn;
    float cosNL = (nx*lx + ny*ly) + nz*lz;
    float diffuse = 0.3f * fmaxf(cosNL, 0.0f);
    float rx = (2.0f * cosNL) * nx - lx;
    float ry = (2.0f * cosNL) * ny - ly;
    float rz = (2.0f * cosNL) * nz - lz;
    float vr = (vx*rx + vy*ry) + vz*rz;
    float spec = 0.12f * powf(fmaxf(vr, 0.0f), 10.0f);
    float sA = 0.5f + diffuse;
    rgb[0] = ((142.0f / 255.0f) * sA + spec) * 255.0f;
    rgb[1] = ((179.0f / 255.0f) * sA + spec) * 255.0f;
    rgb[2] = ((247.0f / 255.0f) * sA + spec) * 255.0f;
}

__global__ void shade(const int2* __restrict__ pix, const float* __restrict__ fd,
                      const float* __restrict__ verts, const int* __restrict__ faces,
                      const float* __restrict__ vn, const float* __restrict__ tm,
                      float* __restrict__ out) {
#pragma clang fp contract(off)
    int t = blockIdx.x * blockDim.x + threadIdx.x;
    if (t >= BATCH * PIX) return;
    int b = t / PIX, p = t % PIX;
    int row = p / H, col = p % H;
    int2 pk = pix[t];
    int fs = pk.x, fr = pk.y;
    float r, g, bc, a;
    if (fs < 0) {
        r = g = bc = 255.0f;
        a = 0.0f;
    } else {
        float px = axf(col), py = axf(row);
        float A[3];
        shade_face(fs, b, px, py, fd, verts, faces, vn, tm, A);
        r = A[0]; g = A[1]; bc = A[2];
        if (fr >= 0) {
            float Bc[3];
            shade_face(fr, b, px, py, fd, verts, faces, vn, tm, Bc);
            float As0 = bf16snap(A[0]), As1 = bf16snap(A[1]), As2 = bf16snap(A[2]);
            float Bs0 = bf16snap(Bc[0]), Bs1 = bf16snap(Bc[1]), Bs2 = bf16snap(Bc[2]);
            if (fabsf(As0 - Bs0) <= 9.01f && fabsf(As1 - Bs1) <= 9.01f &&
                fabsf(As2 - Bs2) <= 9.01f) {
                r  = 0.5f * (As0 + Bs0);
                g  = 0.5f * (As1 + Bs1);
                bc = 0.5f * (As2 + Bs2);
            }
        }
        a = 1.0f;
    }
    out[(((size_t)b*3 + 0) * H + row) * H + col] = r;
    out[(((size_t)b*3 + 1) * H + row) * H + col] = g;
    out[(((size_t)b*3 + 2) * H + row) * H + col] = bc;
    out[(size_t)BATCH*3*H*H + ((size_t)b * H + row) * H + col] = a;
}

extern "C" void kernel_launch(void* const* d_in, const int* in_sizes, int n_in,
                              void* d_out, int out_size, void* d_ws, size_t ws_size,
                              hipStream_t stream) {
    const float* verts = (const float*)d_in[0];
    const float* tm    = (const float*)d_in[1];
    const float* focal = (const float*)d_in[2];
    const int*   faces = (const int*)d_in[3];
    float* out = (float*)d_out;

    char* ws = (char*)d_ws;
    float* fd      = (float*)ws;                     // 1,276,928
    float* vn      = (float*)(ws + 1276928);         //   120,576 ┐
    int*   hist    = (int*)  (ws + 1397504);         //   131,072 ├ one memset
    int*   cursor  = (int*)  (ws + 1528576);         //   131,072 ┘
    int2*  pix     = (int2*) (ws + 1659648);         // 1,048,576
    int*   segArr  = (int*)  (ws + 2708224);         //    79,872
    int*   start   = (int*)  (ws + 2788096);         //   131,080 (NBINS+1, padded)
    ull*   keyS    = (ull*)  (ws + 2919176);         // 4,194,304 (BATCH*ZSPLIT*PIX)
    ull*   keyA    = keyS + (size_t)BATCH * ZSPLIT * PIX;   // 4,194,304
    ull*   keyB    = keyA + (size_t)BATCH * ZSPLIT * PIX;   // 4,194,304 -> 15,502,088
    int*   list    = (int*)  (ws + 15502088);        // rest (ws >= 27.6 MB per r12)
    int cap = (int)((ws_size - 15502088) / 4);

    hipMemsetAsync(vn, 0, 382720, stream);   // vn + hist + cursor contiguous

    setup_all<<<(BATCH * NF + 255) / 256, 256, 0, stream>>>(verts, tm, focal, faces,
                                                            fd, segArr, vn, hist);
    bin_scan<<<1, 1024, 0, stream>>>(hist, start);
    bin_scatter<<<(BATCH * NF + 255) / 256, 256, 0, stream>>>(fd, segArr, start, cursor,
                                                              list, cap, vn);
    dim3 rg(16, 16, BATCH * ZSPLIT);
    raster<<<rg, 256, 0, stream>>>(fd, start, list, keyS, keyA, keyB);

    merge<<<(BATCH * PIX + 255) / 256, 256, 0, stream>>>(keyS, keyA, keyB, pix);

    shade<<<(BATCH * PIX + 255) / 256, 256, 0, stream>>>(pix, fd, verts, faces, vn, tm, out);
}

// Round 18
// 343.421 us; speedup vs baseline: 3.8616x; 3.8616x over previous
//
#include <hip/hip_runtime.h>
#include <stdint.h>

#define H 256
#define PIX (H*H)
#define BATCH 2
#define NV 5023
#define NF 9976
#define EPS 1e-5f
#define CH 128
#define NBUCK 4096

typedef unsigned long long ull;
#define INF_KEY 0x7F800000FFFFFFFFULL

__device__ __forceinline__ float axf(int i) {
    return 1.0f - (2.0f * (float)i + 1.0f) / (float)H;   // exact
}

__device__ __forceinline__ float bf16snap(float x) {     // round-to-nearest-even bf16
    unsigned u = __float_as_uint(x);
    unsigned r = (u + 0x7FFFu + ((u >> 16) & 1u)) & 0xFFFF0000u;
    return __uint_as_float(r);
}

__device__ __forceinline__ int zbucket(float z) {
    int q = (int)floorf((z - 0.5f) * (4096.0f / 3.0f));
    return q < 0 ? 0 : (q > 4095 ? 4095 : q);
}
__device__ __forceinline__ float zbucket_lower(int q) {
    return (q == 0) ? 0.0f : 0.5f + (float)q * (3.0f / 4096.0f);
}

// fd layout (slot permutation; all VALUES byte-identical to r11-r17):
// o[0..3] edge terms | o[4] x2 | o[5] y2 | o[6] den | o[7] okS
// o[8..11] xmn,xmx,ymn,ymx (bbox float4) | o[12..14] z0,z1,z2 | o[15] spare/id
__global__ void face_setup(const float* __restrict__ verts, const float* __restrict__ tm,
                           const float* __restrict__ focal, const int* __restrict__ faces,
                           float* __restrict__ fd, float* __restrict__ zminArr) {
#pragma clang fp contract(off)
    int t = blockIdx.x * blockDim.x + threadIdx.x;
    if (t >= BATCH * NF) return;
    int b = t / NF, f = t % NF;
    const float* M = tm + b * 12;
    float fl = focal[b];
    float X[3], Y[3], Z[3];
#pragma unroll
    for (int k = 0; k < 3; k++) {
        int vi = faces[f * 3 + k];
        const float* v = verts + (b * NV + vi) * 3;
        float v0 = v[0], v1 = v[1], v2 = v[2];
        float c0 = ((v0 * M[0] + v1 * M[4]) + v2 * M[8])  + M[3];
        float c1 = ((v0 * M[1] + v1 * M[5]) + v2 * M[9])  + M[7];
        float c2 = ((v0 * M[2] + v1 * M[6]) + v2 * M[10]) + M[11];
        X[k] = (fl * c0) / c2;
        Y[k] = (fl * c1) / c2;
        Z[k] = c2;
    }
    float x0 = X[0], x1 = X[1], x2 = X[2];
    float y0 = Y[0], y1 = Y[1], y2 = Y[2];
    float z0 = Z[0], z1 = Z[1], z2 = Z[2];
    float den = (y1 - y2) * (x0 - x2) + (x2 - x1) * (y0 - y2);
    bool zv = (z0 > EPS) && (z1 > EPS) && (z2 > EPS);
    bool okS = zv && (fabsf(den) > 1e-8f);
    bool okR = zv && (fabsf(den) > 5e-9f);
    float xmn, xmx, ymn, ymx;
    if (okR) {
        float e01 = (x1 - x0) * (x1 - x0) + (y1 - y0) * (y1 - y0);
        float e12 = (x2 - x1) * (x2 - x1) + (y2 - y1) * (y2 - y1);
        float e20 = (x0 - x2) * (x0 - x2) + (y0 - y2) * (y0 - y2);
        float E2 = fmaxf(fmaxf(e01, e12), e20);
        float delta = 1e-4f * E2 / fabsf(den) + 1e-3f;
        if (!(delta < 4.0f)) delta = 4.0f;
        xmn = fminf(fminf(x0, x1), x2) - delta;
        xmx = fmaxf(fmaxf(x0, x1), x2) + delta;
        ymn = fminf(fminf(y0, y1), y2) - delta;
        ymx = fmaxf(fmaxf(y0, y1), y2) + delta;
    } else {
        xmn = 1e30f; xmx = -1e30f; ymn = 1e30f; ymx = -1e30f;
    }
    float* o = fd + (size_t)t * 16;
    o[0] = y1 - y2;  o[1] = x2 - x1;
    o[2] = y2 - y0;  o[3] = x0 - x2;
    o[4] = x2;       o[5] = y2;
    o[6] = den;      o[7] = okS ? 1.0f : 0.0f;
    o[8] = xmn;  o[9] = xmx;  o[10] = ymn;  o[11] = ymx;
    o[12] = z0;  o[13] = z1;  o[14] = z2;   o[15] = 0.0f;
    zminArr[t] = okR ? fminf(fminf(z0, z1), z2) : -1.0f;
}

__global__ void fn_scatter(const float* __restrict__ verts, const int* __restrict__ faces,
                           float* __restrict__ vn) {
#pragma clang fp contract(off)
    int t = blockIdx.x * blockDim.x + threadIdx.x;
    if (t >= BATCH * NF) return;
    int b = t / NF, f = t % NF;
    int i0 = faces[f*3+0], i1 = faces[f*3+1], i2 = faces[f*3+2];
    const float* vb = verts + b * NV * 3;
    float a0 = vb[i0*3+0], a1 = vb[i0*3+1], a2 = vb[i0*3+2];
    float b0 = vb[i1*3+0], b1 = vb[i1*3+1], b2 = vb[i1*3+2];
    float c0 = vb[i2*3+0], c1 = vb[i2*3+1], c2 = vb[i2*3+2];
    float e1x = b0 - a0, e1y = b1 - a1, e1z = b2 - a2;
    float e2x = c0 - a0, e2y = c1 - a1, e2z = c2 - a2;
    float nx = e1y * e2z - e1z * e2y;
    float ny = e1z * e2x - e1x * e2z;
    float nz = e1x * e2y - e1y * e2x;
    float* nb = vn + (size_t)b * NV * 3;
    atomicAdd(&nb[i0*3+0], nx); atomicAdd(&nb[i0*3+1], ny); atomicAdd(&nb[i0*3+2], nz);
    atomicAdd(&nb[i1*3+0], nx); atomicAdd(&nb[i1*3+1], ny); atomicAdd(&nb[i1*3+2], nz);
    atomicAdd(&nb[i2*3+0], nx); atomicAdd(&nb[i2*3+1], ny); atomicAdd(&nb[i2*3+2], nz);
}

__global__ void vn_normalize(float* __restrict__ vn) {
#pragma clang fp contract(off)
    int t = blockIdx.x * blockDim.x + threadIdx.x;
    if (t >= BATCH * NV) return;
    float x = vn[t*3+0], y = vn[t*3+1], z = vn[t*3+2];
    float n = fmaxf(sqrtf((x*x + y*y) + z*z), 1e-6f);
    vn[t*3+0] = x / n; vn[t*3+1] = y / n; vn[t*3+2] = z / n;
}

// ---- counting sort of okR faces by quantized zmin (per batch), r13 proven ----
__global__ void zhist(const float* __restrict__ zminArr, int* __restrict__ hist) {
    int t = blockIdx.x * blockDim.x + threadIdx.x;
    if (t >= BATCH * NF) return;
    float zm = zminArr[t];
    if (zm < 0.0f) return;
    int b = t / NF;
    atomicAdd(&hist[b * NBUCK + zbucket(zm)], 1);
}

__global__ __launch_bounds__(256) void zscan(const int* __restrict__ hist,
                                             int* __restrict__ start,
                                             int* __restrict__ total) {
    int b = blockIdx.x;
    __shared__ int tot[256];
    int t = threadIdx.x;
    int a[16]; int s = 0;
#pragma unroll
    for (int i = 0; i < 16; i++) { int c = hist[b * NBUCK + t * 16 + i]; a[i] = s; s += c; }
    tot[t] = s;
    __syncthreads();
    for (int off = 1; off < 256; off <<= 1) {
        int x = tot[t];
        if (t >= off) x += tot[t - off];
        __syncthreads();
        tot[t] = x;
        __syncthreads();
    }
    int pre = (t > 0) ? tot[t - 1] : 0;
#pragma unroll
    for (int i = 0; i < 16; i++) start[b * NBUCK + t * 16 + i] = pre + a[i];
    if (t == 255) total[b] = tot[255];
}

__global__ void zscatter(const float* __restrict__ fd, const float* __restrict__ zminArr,
                         const int* __restrict__ start, int* __restrict__ cursor,
                         float* __restrict__ fds, float* __restrict__ blow) {
    int t = blockIdx.x * blockDim.x + threadIdx.x;
    if (t >= BATCH * NF) return;
    float zm = zminArr[t];
    if (zm < 0.0f) return;
    int b = t / NF, f = t % NF;
    int q = zbucket(zm);
    int dst = start[b * NBUCK + q] + atomicAdd(&cursor[b * NBUCK + q], 1);
    const float* o = fd + (size_t)t * 16;
    float* d = fds + ((size_t)b * NF + dst) * 16;
#pragma unroll
    for (int k = 0; k < 15; k++) d[k] = o[k];
    d[15] = __uint_as_float((unsigned)f);          // original face id
    blow[(size_t)b * NF + dst] = zbucket_lower(q); // certified lower bound
}

// quadrant raster on the GLOBAL z-sorted list. One 64-thread wave per 8x8
// pixel quadrant. Coalesced full-chunk stage; bbox compaction; frozen key
// top-2 selection (== r11-r17); relaxed-OR certified break; merge inlined.
__global__ __launch_bounds__(64) void raster(const float* __restrict__ fds,
                                             const float* __restrict__ blow,
                                             const int* __restrict__ total,
                                             int2* __restrict__ pix) {
#pragma clang fp contract(off)
    __shared__ __align__(16) float sfd[CH * 16];
    __shared__ int slist[CH];
    __shared__ int scnt;
    int tid = threadIdx.x;
    int b = blockIdx.z;
    int col0 = blockIdx.x * 8, row0 = blockIdx.y * 8;
    int col = col0 + (tid & 7), row = row0 + (tid >> 3);
    float px = axf(col), py = axf(row);
    float qxmax = axf(col0), qxmin = axf(col0 + 7);
    float qymax = axf(row0), qymin = axf(row0 + 7);
    ull ks = INF_KEY, k1 = INF_KEY, k2 = INF_KEY;
    const float4* fdb4 = (const float4*)(fds + (size_t)b * NF * 16);
    int cntb = total[b];

    for (int fbase = 0; fbase < cntb; fbase += CH) {
        int n = min(CH, cntb - fbase);
        if (tid == 0) scnt = 0;
        // coalesced full stage (contiguous sorted records)
        for (int j = tid; j < n * 4; j += 64)
            ((float4*)sfd)[j] = fdb4[(size_t)fbase * 4 + j];
        __syncthreads();
        // quadrant bbox compaction
        for (int j = tid; j < n; j += 64) {
            const float* o = sfd + j * 16;
            if (o[8] <= qxmax && o[9] >= qxmin && o[10] <= qymax && o[11] >= qymin) {
                int p2 = atomicAdd(&scnt, 1);
                slist[p2] = j;
            }
        }
        __syncthreads();
        int cnt = scnt;
        for (int i = 0; i < cnt; i++) {
            const float* o = sfd + slist[i] * 16;
            bool cand = (px >= o[8]) & (px <= o[9]) & (py >= o[10]) & (py <= o[11]);
            if (__ballot(cand) == 0ULL) continue;
            float dx = px - o[4], dy = py - o[5];
            float w0 = (o[0] * dx + o[1] * dy) / o[6];
            float w1 = (o[2] * dx + o[3] * dy) / o[6];
            float w2 = (1.0f - w0) - w1;
            bool insS = cand && (o[7] != 0.0f) && (w0 >= 0.0f) && (w1 >= 0.0f) && (w2 >= 0.0f);
            bool insR = cand && (w0 >= -1e-5f) && (w1 >= -1e-5f) && (w2 >= -1e-5f);
            if (__ballot(insR) == 0ULL) continue;
            float iz = ((w0 / o[12]) + (w1 / o[13])) + (w2 / o[14]);
            if (insR && (iz > 1e-8f)) {
                float zp = 1.0f / iz;
                ull key = ((ull)__float_as_uint(zp) << 32) |
                          (ull)(unsigned)__float_as_uint(o[15]);
                if (insS && key < ks) ks = key;
                if (key < k1) { k2 = k1; k1 = key; }
                else if (key < k2) { k2 = key; }
            }
        }
        // certified break. OLD: ks,k2 below bound (frozen r13 condition).
        // NEW (proven output-identical): ks set and 1.051*zs < bound_adj --
        // remaining faces (zpix >= bound*(1-3e-5)) can't displace ks/k1 and
        // any k2 change is gate-irrelevant (both fail |zr-zs|<=0.05*zs).
        if (fbase + CH < cntb) {
            float nf = blow[(size_t)b * NF + fbase + CH];
            float madj = nf * (1.0f - 1e-4f);
            float zsv = __uint_as_float((unsigned)(ks >> 32));
            float zbv = __uint_as_float((unsigned)(k2 >> 32));
            bool oldc = (ks != INF_KEY) && (k2 != INF_KEY) && (zsv < madj) && (zbv < madj);
            bool newc = (ks != INF_KEY) && (1.051f * zsv < madj);
            bool done = (nf > 0.0f) && (oldc || newc);
            if (__ballot(!done) == 0ULL) break;
            __syncthreads();
        }
    }
    // inline merge (identical to r13-r17)
    int fs = -1;
    float zs = 0.0f;
    if ((unsigned)(ks >> 32) != 0x7F800000u) {
        fs = (int)(unsigned)ks;
        zs = __uint_as_float((unsigned)(ks >> 32));
    }
    int fr = -1;
    if (fs >= 0) {
        ull mR = INF_KEY;
        if ((int)(unsigned)k1 != fs && k1 < mR) mR = k1;
        if ((int)(unsigned)k2 != fs && k2 < mR) mR = k2;
        if ((unsigned)(mR >> 32) != 0x7F800000u) {
            float zr = __uint_as_float((unsigned)(mR >> 32));
            if (fabsf(zr - zs) <= 0.05f * zs) fr = (int)(unsigned)mR;
        }
    }
    pix[(size_t)b * PIX + (size_t)row * H + col] = make_int2(fs, fr);
}

// faithful f32 shading (identical values to r11-r17; new fd layout)
__device__ void shade_face(int f, int b, float px, float py,
                           const float* __restrict__ fd, const float* __restrict__ verts,
                           const int* __restrict__ faces, const float* __restrict__ vn,
                           const float* __restrict__ tm, float* rgb) {
#pragma clang fp contract(off)
    const float* o = fd + ((size_t)b * NF + f) * 16;
    float dx = px - o[4], dy = py - o[5];
    float w0 = (o[0] * dx + o[1] * dy) / o[6];
    float w1 = (o[2] * dx + o[3] * dy) / o[6];
    float w2 = (1.0f - w0) - w1;
    float q0 = w0 / o[12], q1 = w1 / o[13], q2 = w2 / o[14];
    float iz = (q0 + q1) + q2;
    float zsafe = 1.0f / iz;
    float bw0 = q0 * zsafe, bw1 = q1 * zsafe, bw2 = q2 * zsafe;
    int i0 = faces[f*3+0], i1 = faces[f*3+1], i2 = faces[f*3+2];
    const float* vb = verts + b * NV * 3;
    const float* nb = vn + b * NV * 3;
    float posx = (bw0*vb[i0*3+0] + bw1*vb[i1*3+0]) + bw2*vb[i2*3+0];
    float posy = (bw0*vb[i0*3+1] + bw1*vb[i1*3+1]) + bw2*vb[i2*3+1];
    float posz = (bw0*vb[i0*3+2] + bw1*vb[i1*3+2]) + bw2*vb[i2*3+2];
    float nx = (bw0*nb[i0*3+0] + bw1*nb[i1*3+0]) + bw2*nb[i2*3+0];
    float ny = (bw0*nb[i0*3+1] + bw1*nb[i1*3+1]) + bw2*nb[i2*3+1];
    float nz = (bw0*nb[i0*3+2] + bw1*nb[i1*3+2]) + bw2*nb[i2*3+2];
    float nn = fmaxf(sqrtf((nx*nx + ny*ny) + nz*nz), 1e-6f);
    nx /= nn; ny /= nn; nz /= nn;
    const float* M = tm + b * 12;
    float T0 = M[3], T1 = M[7], T2 = M[11];
    float cpx = -((T0*M[0] + T1*M[1]) + T2*M[2]);
    float cpy = -((T0*M[4] + T1*M[5]) + T2*M[6]);
    float cpz = -((T0*M[8] + T1*M[9]) + T2*M[10]);
    float lx = 0.0f - posx, ly = 1.0f - posy, lz = 3.0f - posz;
    float ln = fmaxf(sqrtf((lx*lx + ly*ly) + lz*lz), 1e-6f);
    lx /= ln; ly /= ln; lz /= ln;
    float vx = cpx - posx, vy = cpy - posy, vz = cpz - posz;
    float vnn = fmaxf(sqrtf((vx*vx + vy*vy) + vz*vz), 1e-6f);
    vx /= vnn; vy /= vnn; vz /= vnn;
    float cosNL = (nx*lx + ny*ly) + nz*lz;
    float diffuse = 0.3f * fmaxf(cosNL, 0.0f);
    float rx = (2.0f * cosNL) * nx - lx;
    float ry = (2.0f * cosNL) * ny - ly;
    float rz = (2.0f * cosNL) * nz - lz;
    float vr = (vx*rx + vy*ry) + vz*rz;
    float spec = 0.12f * powf(fmaxf(vr, 0.0f), 10.0f);
    float sA = 0.5f + diffuse;
    rgb[0] = ((142.0f / 255.0f) * sA + spec) * 255.0f;
    rgb[1] = ((179.0f / 255.0f) * sA + spec) * 255.0f;
    rgb[2] = ((247.0f / 255.0f) * sA + spec) * 255.0f;
}

__global__ void shade(const int2* __restrict__ pix, const float* __restrict__ fd,
                      const float* __restrict__ verts, const int* __restrict__ faces,
                      const float* __restrict__ vn, const float* __restrict__ tm,
                      float* __restrict__ out) {
#pragma clang fp contract(off)
    int t = blockIdx.x * blockDim.x + threadIdx.x;
    if (t >= BATCH * PIX) return;
    int b = t / PIX, p = t % PIX;
    int row = p / H, col = p % H;
    int2 pk = pix[t];
    int fs = pk.x, fr = pk.y;
    float r, g, bc, a;
    if (fs < 0) {
        r = g = bc = 255.0f;
        a = 0.0f;
    } else {
        float px = axf(col), py = axf(row);
        float A[3];
        shade_face(fs, b, px, py, fd, verts, faces, vn, tm, A);
        r = A[0]; g = A[1]; bc = A[2];
        if (fr >= 0) {
            float Bc[3];
            shade_face(fr, b, px, py, fd, verts, faces, vn, tm, Bc);
            float As0 = bf16snap(A[0]), As1 = bf16snap(A[1]), As2 = bf16snap(A[2]);
            float Bs0 = bf16snap(Bc[0]), Bs1 = bf16snap(Bc[1]), Bs2 = bf16snap(Bc[2]);
            if (fabsf(As0 - Bs0) <= 9.01f && fabsf(As1 - Bs1) <= 9.01f &&
                fabsf(As2 - Bs2) <= 9.01f) {
                r  = 0.5f * (As0 + Bs0);
                g  = 0.5f * (As1 + Bs1);
                bc = 0.5f * (As2 + Bs2);
            }
        }
        a = 1.0f;
    }
    out[(((size_t)b*3 + 0) * H + row) * H + col] = r;
    out[(((size_t)b*3 + 1) * H + row) * H + col] = g;
    out[(((size_t)b*3 + 2) * H + row) * H + col] = bc;
    out[(size_t)BATCH*3*H*H + ((size_t)b * H + row) * H + col] = a;
}

extern "C" void kernel_launch(void* const* d_in, const int* in_sizes, int n_in,
                              void* d_out, int out_size, void* d_ws, size_t ws_size,
                              hipStream_t stream) {
    const float* verts = (const float*)d_in[0];
    const float* tm    = (const float*)d_in[1];
    const float* focal = (const float*)d_in[2];
    const int*   faces = (const int*)d_in[3];
    float* out = (float*)d_out;

    char* ws = (char*)d_ws;
    float* fd      = (float*)ws;                     // 1,276,928
    float* vn      = (float*)(ws + 1276928);         //   120,576
    int2*  pix     = (int2*) (ws + 1397504);         // 1,048,576
    float* fds     = (float*)(ws + 2446080);         // 1,276,928
    float* blow    = (float*)(ws + 3723008);         //    79,872
    float* zminArr = (float*)(ws + 3802880);         //    79,872
    int*   hist    = (int*)  (ws + 3882752);         //    32,768
    int*   start   = (int*)  (ws + 3915520);         //    32,768
    int*   cursor  = (int*)  (ws + 3948288);         //    32,768
    int*   total   = (int*)  (ws + 3981056);         //       256

    hipMemsetAsync(vn, 0, (size_t)BATCH * NV * 3 * sizeof(float), stream);
    hipMemsetAsync(hist, 0, (size_t)BATCH * NBUCK * sizeof(int), stream);
    hipMemsetAsync(cursor, 0, (size_t)BATCH * NBUCK * sizeof(int), stream);

    face_setup<<<(BATCH * NF + 255) / 256, 256, 0, stream>>>(verts, tm, focal, faces, fd, zminArr);
    fn_scatter<<<(BATCH * NF + 255) / 256, 256, 0, stream>>>(verts, faces, vn);
    vn_normalize<<<(BATCH * NV + 255) / 256, 256, 0, stream>>>(vn);

    zhist<<<(BATCH * NF + 255) / 256, 256, 0, stream>>>(zminArr, hist);
    zscan<<<BATCH, 256, 0, stream>>>(hist, start, total);
    zscatter<<<(BATCH * NF + 255) / 256, 256, 0, stream>>>(fd, zminArr, start, cursor, fds, blow);

    dim3 rg(32, 32, BATCH);
    raster<<<rg, 64, 0, stream>>>(fds, blow, total, pix);

    shade<<<(BATCH * PIX + 255) / 256, 256, 0, stream>>>(pix, fd, verts, faces, vn, tm, out);
}

// Round 19
// 318.304 us; speedup vs baseline: 4.1663x; 1.0789x over previous
//
#include <hip/hip_runtime.h>
#include <stdint.h>

#define H 256
#define PIX (H*H)
#define BATCH 2
#define NV 5023
#define NF 9976
#define EPS 1e-5f
#define CH 128
#define NBUCK 4096

typedef unsigned long long ull;
#define INF_KEY 0x7F800000FFFFFFFFULL

__device__ __forceinline__ float axf(int i) {
    return 1.0f - (2.0f * (float)i + 1.0f) / (float)H;   // exact
}

__device__ __forceinline__ float bf16snap(float x) {     // round-to-nearest-even bf16
    unsigned u = __float_as_uint(x);
    unsigned r = (u + 0x7FFFu + ((u >> 16) & 1u)) & 0xFFFF0000u;
    return __uint_as_float(r);
}

__device__ __forceinline__ int zbucket(float z) {
    int q = (int)floorf((z - 0.5f) * (4096.0f / 3.0f));
    return q < 0 ? 0 : (q > 4095 ? 4095 : q);
}
__device__ __forceinline__ float zbucket_lower(int q) {
    return (q == 0) ? 0.0f : 0.5f + (float)q * (3.0f / 4096.0f);
}

// fused face setup (arithmetic byte-identical to r11-r18) + fn scatter + zhist
// fd layout: o[0..3] edges | o[4] x2 | o[5] y2 | o[6] den | o[7] okS
//            o[8..11] bbox | o[12..14] z0,z1,z2 | o[15] spare (id after sort)
__global__ void setup_all(const float* __restrict__ verts, const float* __restrict__ tm,
                          const float* __restrict__ focal, const int* __restrict__ faces,
                          float* __restrict__ fd, float* __restrict__ zminArr,
                          float* __restrict__ vn, int* __restrict__ hist) {
#pragma clang fp contract(off)
    int t = blockIdx.x * blockDim.x + threadIdx.x;
    if (t >= BATCH * NF) return;
    int b = t / NF, f = t % NF;
    const float* M = tm + b * 12;
    float fl = focal[b];
    float X[3], Y[3], Z[3];
#pragma unroll
    for (int k = 0; k < 3; k++) {
        int vi = faces[f * 3 + k];
        const float* v = verts + (b * NV + vi) * 3;
        float v0 = v[0], v1 = v[1], v2 = v[2];
        float c0 = ((v0 * M[0] + v1 * M[4]) + v2 * M[8])  + M[3];
        float c1 = ((v0 * M[1] + v1 * M[5]) + v2 * M[9])  + M[7];
        float c2 = ((v0 * M[2] + v1 * M[6]) + v2 * M[10]) + M[11];
        X[k] = (fl * c0) / c2;
        Y[k] = (fl * c1) / c2;
        Z[k] = c2;
    }
    float x0 = X[0], x1 = X[1], x2 = X[2];
    float y0 = Y[0], y1 = Y[1], y2 = Y[2];
    float z0 = Z[0], z1 = Z[1], z2 = Z[2];
    float den = (y1 - y2) * (x0 - x2) + (x2 - x1) * (y0 - y2);
    bool zv = (z0 > EPS) && (z1 > EPS) && (z2 > EPS);
    bool okS = zv && (fabsf(den) > 1e-8f);
    bool okR = zv && (fabsf(den) > 5e-9f);
    float xmn, xmx, ymn, ymx;
    if (okR) {
        float e01 = (x1 - x0) * (x1 - x0) + (y1 - y0) * (y1 - y0);
        float e12 = (x2 - x1) * (x2 - x1) + (y2 - y1) * (y2 - y1);
        float e20 = (x0 - x2) * (x0 - x2) + (y0 - y2) * (y0 - y2);
        float E2 = fmaxf(fmaxf(e01, e12), e20);
        float delta = 1e-4f * E2 / fabsf(den) + 1e-3f;
        if (!(delta < 4.0f)) delta = 4.0f;
        xmn = fminf(fminf(x0, x1), x2) - delta;
        xmx = fmaxf(fmaxf(x0, x1), x2) + delta;
        ymn = fminf(fminf(y0, y1), y2) - delta;
        ymx = fmaxf(fmaxf(y0, y1), y2) + delta;
    } else {
        xmn = 1e30f; xmx = -1e30f; ymn = 1e30f; ymx = -1e30f;
    }
    float* o = fd + (size_t)t * 16;
    o[0] = y1 - y2;  o[1] = x2 - x1;
    o[2] = y2 - y0;  o[3] = x0 - x2;
    o[4] = x2;       o[5] = y2;
    o[6] = den;      o[7] = okS ? 1.0f : 0.0f;
    o[8] = xmn;  o[9] = xmx;  o[10] = ymn;  o[11] = ymx;
    o[12] = z0;  o[13] = z1;  o[14] = z2;   o[15] = 0.0f;
    float zm = okR ? fminf(fminf(z0, z1), z2) : -1.0f;
    zminArr[t] = zm;
    if (zm >= 0.0f) atomicAdd(&hist[b * NBUCK + zbucket(zm)], 1);

    // face-normal scatter (same math as r11-r18)
    {
        int i0 = faces[f*3+0], i1 = faces[f*3+1], i2 = faces[f*3+2];
        const float* vb = verts + b * NV * 3;
        float a0 = vb[i0*3+0], a1 = vb[i0*3+1], a2 = vb[i0*3+2];
        float b0 = vb[i1*3+0], b1 = vb[i1*3+1], b2 = vb[i1*3+2];
        float c0 = vb[i2*3+0], c1 = vb[i2*3+1], c2 = vb[i2*3+2];
        float e1x = b0 - a0, e1y = b1 - a1, e1z = b2 - a2;
        float e2x = c0 - a0, e2y = c1 - a1, e2z = c2 - a2;
        float nx = e1y * e2z - e1z * e2y;
        float ny = e1z * e2x - e1x * e2z;
        float nz = e1x * e2y - e1y * e2x;
        float* nb = vn + (size_t)b * NV * 3;
        atomicAdd(&nb[i0*3+0], nx); atomicAdd(&nb[i0*3+1], ny); atomicAdd(&nb[i0*3+2], nz);
        atomicAdd(&nb[i1*3+0], nx); atomicAdd(&nb[i1*3+1], ny); atomicAdd(&nb[i1*3+2], nz);
        atomicAdd(&nb[i2*3+0], nx); atomicAdd(&nb[i2*3+1], ny); atomicAdd(&nb[i2*3+2], nz);
    }
}

__global__ __launch_bounds__(256) void zscan(const int* __restrict__ hist,
                                             int* __restrict__ start,
                                             int* __restrict__ total) {
    int b = blockIdx.x;
    __shared__ int tot[256];
    int t = threadIdx.x;
    int a[16]; int s = 0;
#pragma unroll
    for (int i = 0; i < 16; i++) { int c = hist[b * NBUCK + t * 16 + i]; a[i] = s; s += c; }
    tot[t] = s;
    __syncthreads();
    for (int off = 1; off < 256; off <<= 1) {
        int x = tot[t];
        if (t >= off) x += tot[t - off];
        __syncthreads();
        tot[t] = x;
        __syncthreads();
    }
    int pre = (t > 0) ? tot[t - 1] : 0;
#pragma unroll
    for (int i = 0; i < 16; i++) start[b * NBUCK + t * 16 + i] = pre + a[i];
    if (t == 255) total[b] = tot[255];
}

// z-sort scatter + fused vertex-normal normalize
__global__ void zscatter(const float* __restrict__ fd, const float* __restrict__ zminArr,
                         const int* __restrict__ start, int* __restrict__ cursor,
                         float* __restrict__ fds, float* __restrict__ blow,
                         float* __restrict__ vn) {
#pragma clang fp contract(off)
    int t = blockIdx.x * blockDim.x + threadIdx.x;
    if (t < BATCH * NV) {
        float x = vn[t*3+0], y = vn[t*3+1], z = vn[t*3+2];
        float n = fmaxf(sqrtf((x*x + y*y) + z*z), 1e-6f);
        vn[t*3+0] = x / n; vn[t*3+1] = y / n; vn[t*3+2] = z / n;
    }
    if (t >= BATCH * NF) return;
    float zm = zminArr[t];
    if (zm < 0.0f) return;
    int b = t / NF, f = t % NF;
    int q = zbucket(zm);
    int dst = start[b * NBUCK + q] + atomicAdd(&cursor[b * NBUCK + q], 1);
    const float* o = fd + (size_t)t * 16;
    float* d = fds + ((size_t)b * NF + dst) * 16;
#pragma unroll
    for (int k = 0; k < 15; k++) d[k] = o[k];
    d[15] = __uint_as_float((unsigned)f);          // original face id
    blow[(size_t)b * NF + dst] = zbucket_lower(q); // certified lower bound
}

// quadrant raster on the GLOBAL z-sorted list. One 64-thread wave per 8x8
// quadrant. 3-phase chunk: bbox-only stage (conflict-free SoA), compaction,
// survivor-only full gather. Selection + relaxed-OR break frozen from r18.
__global__ __launch_bounds__(64) void raster(const float* __restrict__ fds,
                                             const float* __restrict__ blow,
                                             const int* __restrict__ total,
                                             int2* __restrict__ pix) {
#pragma clang fp contract(off)
    __shared__ __align__(16) float4 sbb[CH];
    __shared__ __align__(16) float sfd[CH * 16];
    __shared__ int slist[CH];
    __shared__ int scnt;
    int tid = threadIdx.x;
    int b = blockIdx.z;
    int col0 = blockIdx.x * 8, row0 = blockIdx.y * 8;
    int col = col0 + (tid & 7), row = row0 + (tid >> 3);
    float px = axf(col), py = axf(row);
    float qxmax = axf(col0), qxmin = axf(col0 + 7);
    float qymax = axf(row0), qymin = axf(row0 + 7);
    ull ks = INF_KEY, k1 = INF_KEY, k2 = INF_KEY;
    const float4* fdb4 = (const float4*)(fds + (size_t)b * NF * 16);
    int cntb = total[b];

    for (int fbase = 0; fbase < cntb; fbase += CH) {
        int n = min(CH, cntb - fbase);
        if (tid == 0) scnt = 0;
        // phase 1: bbox-only stage (consecutive float4 -> conflict-free)
        for (int j = tid; j < n; j += 64)
            sbb[j] = fdb4[(size_t)(fbase + j) * 4 + 2];
        __syncthreads();
        // phase 2: quadrant bbox compaction
        for (int j = tid; j < n; j += 64) {
            float4 bb = sbb[j];
            if (bb.x <= qxmax && bb.y >= qxmin && bb.z <= qymax && bb.w >= qymin) {
                int p2 = atomicAdd(&scnt, 1);
                slist[p2] = j;
            }
        }
        __syncthreads();
        int cnt = scnt;
        // phase 3: survivor-only full gather (packed; id already in o[15])
        for (int j = tid; j < cnt * 4; j += 64) {
            int e = fbase + slist[j >> 2];
            ((float4*)sfd)[j] = fdb4[(size_t)e * 4 + (j & 3)];
        }
        __syncthreads();
        for (int i = 0; i < cnt; i++) {
            const float* o = sfd + i * 16;
            bool cand = (px >= o[8]) & (px <= o[9]) & (py >= o[10]) & (py <= o[11]);
            if (__ballot(cand) == 0ULL) continue;
            float dx = px - o[4], dy = py - o[5];
            float w0 = (o[0] * dx + o[1] * dy) / o[6];
            float w1 = (o[2] * dx + o[3] * dy) / o[6];
            float w2 = (1.0f - w0) - w1;
            bool insS = cand && (o[7] != 0.0f) && (w0 >= 0.0f) && (w1 >= 0.0f) && (w2 >= 0.0f);
            bool insR = cand && (w0 >= -1e-5f) && (w1 >= -1e-5f) && (w2 >= -1e-5f);
            if (__ballot(insR) == 0ULL) continue;
            float iz = ((w0 / o[12]) + (w1 / o[13])) + (w2 / o[14]);
            if (insR && (iz > 1e-8f)) {
                float zp = 1.0f / iz;
                ull key = ((ull)__float_as_uint(zp) << 32) |
                          (ull)(unsigned)__float_as_uint(o[15]);
                if (insS && key < ks) ks = key;
                if (key < k1) { k2 = k1; k1 = key; }
                else if (key < k2) { k2 = key; }
            }
        }
        // certified break (frozen r18 OLD||NEW condition)
        if (fbase + CH < cntb) {
            float nf = blow[(size_t)b * NF + fbase + CH];
            float madj = nf * (1.0f - 1e-4f);
            float zsv = __uint_as_float((unsigned)(ks >> 32));
            float zbv = __uint_as_float((unsigned)(k2 >> 32));
            bool oldc = (ks != INF_KEY) && (k2 != INF_KEY) && (zsv < madj) && (zbv < madj);
            bool newc = (ks != INF_KEY) && (1.051f * zsv < madj);
            bool done = (nf > 0.0f) && (oldc || newc);
            if (__ballot(!done) == 0ULL) break;
            __syncthreads();
        }
    }
    // inline merge (identical to r13-r18)
    int fs = -1;
    float zs = 0.0f;
    if ((unsigned)(ks >> 32) != 0x7F800000u) {
        fs = (int)(unsigned)ks;
        zs = __uint_as_float((unsigned)(ks >> 32));
    }
    int fr = -1;
    if (fs >= 0) {
        ull mR = INF_KEY;
        if ((int)(unsigned)k1 != fs && k1 < mR) mR = k1;
        if ((int)(unsigned)k2 != fs && k2 < mR) mR = k2;
        if ((unsigned)(mR >> 32) != 0x7F800000u) {
            float zr = __uint_as_float((unsigned)(mR >> 32));
            if (fabsf(zr - zs) <= 0.05f * zs) fr = (int)(unsigned)mR;
        }
    }
    pix[(size_t)b * PIX + (size_t)row * H + col] = make_int2(fs, fr);
}

// faithful f32 shading (identical values to r11-r18)
__device__ void shade_face(int f, int b, float px, float py,
                           const float* __restrict__ fd, const float* __restrict__ verts,
                           const int* __restrict__ faces, const float* __restrict__ vn,
                           const float* __restrict__ tm, float* rgb) {
#pragma clang fp contract(off)
    const float* o = fd + ((size_t)b * NF + f) * 16;
    float dx = px - o[4], dy = py - o[5];
    float w0 = (o[0] * dx + o[1] * dy) / o[6];
    float w1 = (o[2] * dx + o[3] * dy) / o[6];
    float w2 = (1.0f - w0) - w1;
    float q0 = w0 / o[12], q1 = w1 / o[13], q2 = w2 / o[14];
    float iz = (q0 + q1) + q2;
    float zsafe = 1.0f / iz;
    float bw0 = q0 * zsafe, bw1 = q1 * zsafe, bw2 = q2 * zsafe;
    int i0 = faces[f*3+0], i1 = faces[f*3+1], i2 = faces[f*3+2];
    const float* vb = verts + b * NV * 3;
    const float* nb = vn + b * NV * 3;
    float posx = (bw0*vb[i0*3+0] + bw1*vb[i1*3+0]) + bw2*vb[i2*3+0];
    float posy = (bw0*vb[i0*3+1] + bw1*vb[i1*3+1]) + bw2*vb[i2*3+1];
    float posz = (bw0*vb[i0*3+2] + bw1*vb[i1*3+2]) + bw2*vb[i2*3+2];
    float nx = (bw0*nb[i0*3+0] + bw1*nb[i1*3+0]) + bw2*nb[i2*3+0];
    float ny = (bw0*nb[i0*3+1] + bw1*nb[i1*3+1]) + bw2*nb[i2*3+1];
    float nz = (bw0*nb[i0*3+2] + bw1*nb[i1*3+2]) + bw2*nb[i2*3+2];
    float nn = fmaxf(sqrtf((nx*nx + ny*ny) + nz*nz), 1e-6f);
    nx /= nn; ny /= nn; nz /= nn;
    const float* M = tm + b * 12;
    float T0 = M[3], T1 = M[7], T2 = M[11];
    float cpx = -((T0*M[0] + T1*M[1]) + T2*M[2]);
    float cpy = -((T0*M[4] + T1*M[5]) + T2*M[6]);
    float cpz = -((T0*M[8] + T1*M[9]) + T2*M[10]);
    float lx = 0.0f - posx, ly = 1.0f - posy, lz = 3.0f - posz;
    float ln = fmaxf(sqrtf((lx*lx + ly*ly) + lz*lz), 1e-6f);
    lx /= ln; ly /= ln; lz /= ln;
    float vx = cpx - posx, vy = cpy - posy, vz = cpz - posz;
    float vnn = fmaxf(sqrtf((vx*vx + vy*vy) + vz*vz), 1e-6f);
    vx /= vnn; vy /= vnn; vz /= vnn;
    float cosNL = (nx*lx + ny*ly) + nz*lz;
    float diffuse = 0.3f * fmaxf(cosNL, 0.0f);
    float rx = (2.0f * cosNL) * nx - lx;
    float ry = (2.0f * cosNL) * ny - ly;
    float rz = (2.0f * cosNL) * nz - lz;
    float vr = (vx*rx + vy*ry) + vz*rz;
    float spec = 0.12f * powf(fmaxf(vr, 0.0f), 10.0f);
    float sA = 0.5f + diffuse;
    rgb[0] = ((142.0f / 255.0f) * sA + spec) * 255.0f;
    rgb[1] = ((179.0f / 255.0f) * sA + spec) * 255.0f;
    rgb[2] = ((247.0f / 255.0f) * sA + spec) * 255.0f;
}

__global__ void shade(const int2* __restrict__ pix, const float* __restrict__ fd,
                      const float* __restrict__ verts, const int* __restrict__ faces,
                      const float* __restrict__ vn, const float* __restrict__ tm,
                      float* __restrict__ out) {
#pragma clang fp contract(off)
    int t = blockIdx.x * blockDim.x + threadIdx.x;
    if (t >= BATCH * PIX) return;
    int b = t / PIX, p = t % PIX;
    int row = p / H, col = p % H;
    int2 pk = pix[t];
    int fs = pk.x, fr = pk.y;
    float r, g, bc, a;
    if (fs < 0) {
        r = g = bc = 255.0f;
        a = 0.0f;
    } else {
        float px = axf(col), py = axf(row);
        float A[3];
        shade_face(fs, b, px, py, fd, verts, faces, vn, tm, A);
        r = A[0]; g = A[1]; bc = A[2];
        if (fr >= 0) {
            float Bc[3];
            shade_face(fr, b, px, py, fd, verts, faces, vn, tm, Bc);
            float As0 = bf16snap(A[0]), As1 = bf16snap(A[1]), As2 = bf16snap(A[2]);
            float Bs0 = bf16snap(Bc[0]), Bs1 = bf16snap(Bc[1]), Bs2 = bf16snap(Bc[2]);
            if (fabsf(As0 - Bs0) <= 9.01f && fabsf(As1 - Bs1) <= 9.01f &&
                fabsf(As2 - Bs2) <= 9.01f) {
                r  = 0.5f * (As0 + Bs0);
                g  = 0.5f * (As1 + Bs1);
                bc = 0.5f * (As2 + Bs2);
            }
        }
        a = 1.0f;
    }
    out[(((size_t)b*3 + 0) * H + row) * H + col] = r;
    out[(((size_t)b*3 + 1) * H + row) * H + col] = g;
    out[(((size_t)b*3 + 2) * H + row) * H + col] = bc;
    out[(size_t)BATCH*3*H*H + ((size_t)b * H + row) * H + col] = a;
}

extern "C" void kernel_launch(void* const* d_in, const int* in_sizes, int n_in,
                              void* d_out, int out_size, void* d_ws, size_t ws_size,
                              hipStream_t stream) {
    const float* verts = (const float*)d_in[0];
    const float* tm    = (const float*)d_in[1];
    const float* focal = (const float*)d_in[2];
    const int*   faces = (const int*)d_in[3];
    float* out = (float*)d_out;

    char* ws = (char*)d_ws;
    float* fd      = (float*)ws;                     // 1,276,928
    float* vn      = (float*)(ws + 1276928);         //   120,576 ┐
    int*   hist    = (int*)  (ws + 1397504);         //    32,768 ├ one memset (186,112 B)
    int*   cursor  = (int*)  (ws + 1430272);         //    32,768 ┘
    int2*  pix     = (int2*) (ws + 1463040);         // 1,048,576
    float* fds     = (float*)(ws + 2511616);         // 1,276,928
    float* blow    = (float*)(ws + 3788544);         //    79,872
    float* zminArr = (float*)(ws + 3868416);         //    79,872
    int*   start   = (int*)  (ws + 3948288);         //    32,768
    int*   total   = (int*)  (ws + 3981056);         //       256

    hipMemsetAsync(vn, 0, 186112, stream);           // vn + hist + cursor

    setup_all<<<(BATCH * NF + 255) / 256, 256, 0, stream>>>(verts, tm, focal, faces,
                                                            fd, zminArr, vn, hist);
    zscan<<<BATCH, 256, 0, stream>>>(hist, start, total);
    zscatter<<<(BATCH * NF + 255) / 256, 256, 0, stream>>>(fd, zminArr, start, cursor,
                                                           fds, blow, vn);
    dim3 rg(32, 32, BATCH);
    raster<<<rg, 64, 0, stream>>>(fds, blow, total, pix);

    shade<<<(BATCH * PIX + 255) / 256, 256, 0, stream>>>(pix, fd, verts, faces, vn, tm, out);
}

// Round 20
// 299.697 us; speedup vs baseline: 4.4250x; 1.0621x over previous
//
#include <hip/hip_runtime.h>
#include <stdint.h>

#define H 256
#define PIX (H*H)
#define BATCH 2
#define NV 5023
#define NF 9976
#define EPS 1e-5f
#define CH 128
#define NBUCK 4096

typedef unsigned long long ull;
#define INF_KEY 0x7F800000FFFFFFFFULL

__device__ __forceinline__ float axf(int i) {
    return 1.0f - (2.0f * (float)i + 1.0f) / (float)H;   // exact
}

__device__ __forceinline__ float bf16snap(float x) {     // round-to-nearest-even bf16
    unsigned u = __float_as_uint(x);
    unsigned r = (u + 0x7FFFu + ((u >> 16) & 1u)) & 0xFFFF0000u;
    return __uint_as_float(r);
}

__device__ __forceinline__ int zbucket(float z) {
    int q = (int)floorf((z - 0.5f) * (4096.0f / 3.0f));
    return q < 0 ? 0 : (q > 4095 ? 4095 : q);
}
__device__ __forceinline__ float zbucket_lower(int q) {
    return (q == 0) ? 0.0f : 0.5f + (float)q * (3.0f / 4096.0f);
}

// fused face setup (arithmetic byte-identical to r11-r19) + fn scatter + zhist
__global__ void setup_all(const float* __restrict__ verts, const float* __restrict__ tm,
                          const float* __restrict__ focal, const int* __restrict__ faces,
                          float* __restrict__ fd, float* __restrict__ zminArr,
                          float* __restrict__ vn, int* __restrict__ hist) {
#pragma clang fp contract(off)
    int t = blockIdx.x * blockDim.x + threadIdx.x;
    if (t >= BATCH * NF) return;
    int b = t / NF, f = t % NF;
    const float* M = tm + b * 12;
    float fl = focal[b];
    float X[3], Y[3], Z[3];
#pragma unroll
    for (int k = 0; k < 3; k++) {
        int vi = faces[f * 3 + k];
        const float* v = verts + (b * NV + vi) * 3;
        float v0 = v[0], v1 = v[1], v2 = v[2];
        float c0 = ((v0 * M[0] + v1 * M[4]) + v2 * M[8])  + M[3];
        float c1 = ((v0 * M[1] + v1 * M[5]) + v2 * M[9])  + M[7];
        float c2 = ((v0 * M[2] + v1 * M[6]) + v2 * M[10]) + M[11];
        X[k] = (fl * c0) / c2;
        Y[k] = (fl * c1) / c2;
        Z[k] = c2;
    }
    float x0 = X[0], x1 = X[1], x2 = X[2];
    float y0 = Y[0], y1 = Y[1], y2 = Y[2];
    float z0 = Z[0], z1 = Z[1], z2 = Z[2];
    float den = (y1 - y2) * (x0 - x2) + (x2 - x1) * (y0 - y2);
    bool zv = (z0 > EPS) && (z1 > EPS) && (z2 > EPS);
    bool okS = zv && (fabsf(den) > 1e-8f);
    bool okR = zv && (fabsf(den) > 5e-9f);
    float xmn, xmx, ymn, ymx;
    if (okR) {
        float e01 = (x1 - x0) * (x1 - x0) + (y1 - y0) * (y1 - y0);
        float e12 = (x2 - x1) * (x2 - x1) + (y2 - y1) * (y2 - y1);
        float e20 = (x0 - x2) * (x0 - x2) + (y0 - y2) * (y0 - y2);
        float E2 = fmaxf(fmaxf(e01, e12), e20);
        float delta = 1e-4f * E2 / fabsf(den) + 1e-3f;
        if (!(delta < 4.0f)) delta = 4.0f;
        xmn = fminf(fminf(x0, x1), x2) - delta;
        xmx = fmaxf(fmaxf(x0, x1), x2) + delta;
        ymn = fminf(fminf(y0, y1), y2) - delta;
        ymx = fmaxf(fmaxf(y0, y1), y2) + delta;
    } else {
        xmn = 1e30f; xmx = -1e30f; ymn = 1e30f; ymx = -1e30f;
    }
    float* o = fd + (size_t)t * 16;
    o[0] = y1 - y2;  o[1] = x2 - x1;
    o[2] = y2 - y0;  o[3] = x0 - x2;
    o[4] = x2;       o[5] = y2;
    o[6] = den;      o[7] = okS ? 1.0f : 0.0f;
    o[8] = xmn;  o[9] = xmx;  o[10] = ymn;  o[11] = ymx;
    o[12] = z0;  o[13] = z1;  o[14] = z2;   o[15] = 0.0f;
    float zm = okR ? fminf(fminf(z0, z1), z2) : -1.0f;
    zminArr[t] = zm;
    if (zm >= 0.0f) atomicAdd(&hist[b * NBUCK + zbucket(zm)], 1);

    // face-normal scatter (same math as r11-r19)
    {
        int i0 = faces[f*3+0], i1 = faces[f*3+1], i2 = faces[f*3+2];
        const float* vb = verts + b * NV * 3;
        float a0 = vb[i0*3+0], a1 = vb[i0*3+1], a2 = vb[i0*3+2];
        float b0 = vb[i1*3+0], b1 = vb[i1*3+1], b2 = vb[i1*3+2];
        float c0 = vb[i2*3+0], c1 = vb[i2*3+1], c2 = vb[i2*3+2];
        float e1x = b0 - a0, e1y = b1 - a1, e1z = b2 - a2;
        float e2x = c0 - a0, e2y = c1 - a1, e2z = c2 - a2;
        float nx = e1y * e2z - e1z * e2y;
        float ny = e1z * e2x - e1x * e2z;
        float nz = e1x * e2y - e1y * e2x;
        float* nb = vn + (size_t)b * NV * 3;
        atomicAdd(&nb[i0*3+0], nx); atomicAdd(&nb[i0*3+1], ny); atomicAdd(&nb[i0*3+2], nz);
        atomicAdd(&nb[i1*3+0], nx); atomicAdd(&nb[i1*3+1], ny); atomicAdd(&nb[i1*3+2], nz);
        atomicAdd(&nb[i2*3+0], nx); atomicAdd(&nb[i2*3+1], ny); atomicAdd(&nb[i2*3+2], nz);
    }
}

__global__ __launch_bounds__(256) void zscan(const int* __restrict__ hist,
                                             int* __restrict__ start,
                                             int* __restrict__ total) {
    int b = blockIdx.x;
    __shared__ int tot[256];
    int t = threadIdx.x;
    int a[16]; int s = 0;
#pragma unroll
    for (int i = 0; i < 16; i++) { int c = hist[b * NBUCK + t * 16 + i]; a[i] = s; s += c; }
    tot[t] = s;
    __syncthreads();
    for (int off = 1; off < 256; off <<= 1) {
        int x = tot[t];
        if (t >= off) x += tot[t - off];
        __syncthreads();
        tot[t] = x;
        __syncthreads();
    }
    int pre = (t > 0) ? tot[t - 1] : 0;
#pragma unroll
    for (int i = 0; i < 16; i++) start[b * NBUCK + t * 16 + i] = pre + a[i];
    if (t == 255) total[b] = tot[255];
}

// z-sort scatter + fused vertex-normal normalize
__global__ void zscatter(const float* __restrict__ fd, const float* __restrict__ zminArr,
                         const int* __restrict__ start, int* __restrict__ cursor,
                         float* __restrict__ fds, float* __restrict__ blow,
                         float* __restrict__ vn) {
#pragma clang fp contract(off)
    int t = blockIdx.x * blockDim.x + threadIdx.x;
    if (t < BATCH * NV) {
        float x = vn[t*3+0], y = vn[t*3+1], z = vn[t*3+2];
        float n = fmaxf(sqrtf((x*x + y*y) + z*z), 1e-6f);
        vn[t*3+0] = x / n; vn[t*3+1] = y / n; vn[t*3+2] = z / n;
    }
    if (t >= BATCH * NF) return;
    float zm = zminArr[t];
    if (zm < 0.0f) return;
    int b = t / NF, f = t % NF;
    int q = zbucket(zm);
    int dst = start[b * NBUCK + q] + atomicAdd(&cursor[b * NBUCK + q], 1);
    const float* o = fd + (size_t)t * 16;
    float* d = fds + ((size_t)b * NF + dst) * 16;
#pragma unroll
    for (int k = 0; k < 15; k++) d[k] = o[k];
    d[15] = __uint_as_float((unsigned)f);          // original face id
    blow[(size_t)b * NF + dst] = zbucket_lower(q); // certified lower bound
}

// quadrant raster, CU-swizzled. 3-phase chunk (bbox stage, compaction,
// survivor gather) + divide-free conservative pre-filter before the frozen
// exact eval. Selection keys + relaxed-OR break byte-identical to r18/r19.
__global__ __launch_bounds__(64) void raster(const float* __restrict__ fds,
                                             const float* __restrict__ blow,
                                             const int* __restrict__ total,
                                             int2* __restrict__ pix) {
#pragma clang fp contract(off)
    __shared__ __align__(16) float4 sbb[CH];
    __shared__ __align__(16) float sfd[CH * 16];
    __shared__ int slist[CH];
    __shared__ int scnt;
    int tid = threadIdx.x;
    int b = blockIdx.z;
    // swizzle quadrant id across CUs (odd multiplier -> bijection on 1024)
    int id = blockIdx.y * 32 + blockIdx.x;
    int sw = (id * 733) & 1023;
    int col0 = (sw & 31) * 8, row0 = (sw >> 5) * 8;
    int col = col0 + (tid & 7), row = row0 + (tid >> 3);
    float px = axf(col), py = axf(row);
    float qxmax = axf(col0), qxmin = axf(col0 + 7);
    float qymax = axf(row0), qymin = axf(row0 + 7);
    ull ks = INF_KEY, k1 = INF_KEY, k2 = INF_KEY;
    const float4* fdb4 = (const float4*)(fds + (size_t)b * NF * 16);
    int cntb = total[b];

    for (int fbase = 0; fbase < cntb; fbase += CH) {
        int n = min(CH, cntb - fbase);
        if (tid == 0) scnt = 0;
        // phase 1: bbox-only stage
        for (int j = tid; j < n; j += 64)
            sbb[j] = fdb4[(size_t)(fbase + j) * 4 + 2];
        __syncthreads();
        // phase 2: quadrant bbox compaction
        for (int j = tid; j < n; j += 64) {
            float4 bb = sbb[j];
            if (bb.x <= qxmax && bb.y >= qxmin && bb.z <= qymax && bb.w >= qymin) {
                int p2 = atomicAdd(&scnt, 1);
                slist[p2] = j;
            }
        }
        __syncthreads();
        int cnt = scnt;
        // phase 3: survivor-only full gather
        for (int j = tid; j < cnt * 4; j += 64) {
            int e = fbase + slist[j >> 2];
            ((float4*)sfd)[j] = fdb4[(size_t)e * 4 + (j & 3)];
        }
        __syncthreads();
        for (int i = 0; i < cnt; i++) {
            const float* o = sfd + i * 16;
            bool cand = (px >= o[8]) & (px <= o[9]) & (py >= o[10]) & (py <= o[11]);
            if (__ballot(cand) == 0ULL) continue;
            float dx = px - o[4], dy = py - o[5];
            float num0 = o[0] * dx + o[1] * dy;   // same expression tree as eval
            float num1 = o[2] * dx + o[3] * dy;
            // divide-free conservative pre-filter: reject only when the exact
            // frozen eval PROVABLY fails both insS and insR.
            //  n_s < -2e-5*|den|  => fl(w) < -1.99e-5 < -1e-5  (both fail)
            //  n0s+n1s > 1.001*|den| => fl(w2) < -8e-4 < -1e-5 (both fail)
            float adsn = fabsf(o[6]);
            float dsgn = (o[6] > 0.0f) ? 1.0f : -1.0f;
            float n0s = num0 * dsgn, n1s = num1 * dsgn;
            float thr = 2e-5f * adsn, thr2 = 1.001f * adsn;
            bool plaus = cand && (n0s >= -thr) && (n1s >= -thr) && ((n0s + n1s) <= thr2);
            if (__ballot(plaus) == 0ULL) continue;
            if (plaus) {
                float w0 = num0 / o[6];
                float w1 = num1 / o[6];
                float w2 = (1.0f - w0) - w1;
                bool insS = (o[7] != 0.0f) && (w0 >= 0.0f) && (w1 >= 0.0f) && (w2 >= 0.0f);
                bool insR = (w0 >= -1e-5f) && (w1 >= -1e-5f) && (w2 >= -1e-5f);
                if (insR) {
                    float iz = ((w0 / o[12]) + (w1 / o[13])) + (w2 / o[14]);
                    if (iz > 1e-8f) {
                        float zp = 1.0f / iz;
                        ull key = ((ull)__float_as_uint(zp) << 32) |
                                  (ull)(unsigned)__float_as_uint(o[15]);
                        if (insS && key < ks) ks = key;
                        if (key < k1) { k2 = k1; k1 = key; }
                        else if (key < k2) { k2 = key; }
                    }
                }
            }
        }
        // certified break (frozen r18 OLD||NEW condition)
        if (fbase + CH < cntb) {
            float nf = blow[(size_t)b * NF + fbase + CH];
            float madj = nf * (1.0f - 1e-4f);
            float zsv = __uint_as_float((unsigned)(ks >> 32));
            float zbv = __uint_as_float((unsigned)(k2 >> 32));
            bool oldc = (ks != INF_KEY) && (k2 != INF_KEY) && (zsv < madj) && (zbv < madj);
            bool newc = (ks != INF_KEY) && (1.051f * zsv < madj);
            bool done = (nf > 0.0f) && (oldc || newc);
            if (__ballot(!done) == 0ULL) break;
            __syncthreads();
        }
    }
    // inline merge (identical to r13-r19)
    int fs = -1;
    float zs = 0.0f;
    if ((unsigned)(ks >> 32) != 0x7F800000u) {
        fs = (int)(unsigned)ks;
        zs = __uint_as_float((unsigned)(ks >> 32));
    }
    int fr = -1;
    if (fs >= 0) {
        ull mR = INF_KEY;
        if ((int)(unsigned)k1 != fs && k1 < mR) mR = k1;
        if ((int)(unsigned)k2 != fs && k2 < mR) mR = k2;
        if ((unsigned)(mR >> 32) != 0x7F800000u) {
            float zr = __uint_as_float((unsigned)(mR >> 32));
            if (fabsf(zr - zs) <= 0.05f * zs) fr = (int)(unsigned)mR;
        }
    }
    pix[(size_t)b * PIX + (size_t)row * H + col] = make_int2(fs, fr);
}

// faithful f32 shading (identical values to r11-r19)
__device__ void shade_face(int f, int b, float px, float py,
                           const float* __restrict__ fd, const float* __restrict__ verts,
                           const int* __restrict__ faces, const float* __restrict__ vn,
                           const float* __restrict__ tm, float* rgb) {
#pragma clang fp contract(off)
    const float* o = fd + ((size_t)b * NF + f) * 16;
    float dx = px - o[4], dy = py - o[5];
    float w0 = (o[0] * dx + o[1] * dy) / o[6];
    float w1 = (o[2] * dx + o[3] * dy) / o[6];
    float w2 = (1.0f - w0) - w1;
    float q0 = w0 / o[12], q1 = w1 / o[13], q2 = w2 / o[14];
    float iz = (q0 + q1) + q2;
    float zsafe = 1.0f / iz;
    float bw0 = q0 * zsafe, bw1 = q1 * zsafe, bw2 = q2 * zsafe;
    int i0 = faces[f*3+0], i1 = faces[f*3+1], i2 = faces[f*3+2];
    const float* vb = verts + b * NV * 3;
    const float* nb = vn + b * NV * 3;
    float posx = (bw0*vb[i0*3+0] + bw1*vb[i1*3+0]) + bw2*vb[i2*3+0];
    float posy = (bw0*vb[i0*3+1] + bw1*vb[i1*3+1]) + bw2*vb[i2*3+1];
    float posz = (bw0*vb[i0*3+2] + bw1*vb[i1*3+2]) + bw2*vb[i2*3+2];
    float nx = (bw0*nb[i0*3+0] + bw1*nb[i1*3+0]) + bw2*nb[i2*3+0];
    float ny = (bw0*nb[i0*3+1] + bw1*nb[i1*3+1]) + bw2*nb[i2*3+1];
    float nz = (bw0*nb[i0*3+2] + bw1*nb[i1*3+2]) + bw2*nb[i2*3+2];
    float nn = fmaxf(sqrtf((nx*nx + ny*ny) + nz*nz), 1e-6f);
    nx /= nn; ny /= nn; nz /= nn;
    const float* M = tm + b * 12;
    float T0 = M[3], T1 = M[7], T2 = M[11];
    float cpx = -((T0*M[0] + T1*M[1]) + T2*M[2]);
    float cpy = -((T0*M[4] + T1*M[5]) + T2*M[6]);
    float cpz = -((T0*M[8] + T1*M[9]) + T2*M[10]);
    float lx = 0.0f - posx, ly = 1.0f - posy, lz = 3.0f - posz;
    float ln = fmaxf(sqrtf((lx*lx + ly*ly) + lz*lz), 1e-6f);
    lx /= ln; ly /= ln; lz /= ln;
    float vx = cpx - posx, vy = cpy - posy, vz = cpz - posz;
    float vnn = fmaxf(sqrtf((vx*vx + vy*vy) + vz*vz), 1e-6f);
    vx /= vnn; vy /= vnn; vz /= vnn;
    float cosNL = (nx*lx + ny*ly) + nz*lz;
    float diffuse = 0.3f * fmaxf(cosNL, 0.0f);
    float rx = (2.0f * cosNL) * nx - lx;
    float ry = (2.0f * cosNL) * ny - ly;
    float rz = (2.0f * cosNL) * nz - lz;
    float vr = (vx*rx + vy*ry) + vz*rz;
    float spec = 0.12f * powf(fmaxf(vr, 0.0f), 10.0f);
    float sA = 0.5f + diffuse;
    rgb[0] = ((142.0f / 255.0f) * sA + spec) * 255.0f;
    rgb[1] = ((179.0f / 255.0f) * sA + spec) * 255.0f;
    rgb[2] = ((247.0f / 255.0f) * sA + spec) * 255.0f;
}

__global__ void shade(const int2* __restrict__ pix, const float* __restrict__ fd,
                      const float* __restrict__ verts, const int* __restrict__ faces,
                      const float* __restrict__ vn, const float* __restrict__ tm,
                      float* __restrict__ out) {
#pragma clang fp contract(off)
    int t = blockIdx.x * blockDim.x + threadIdx.x;
    if (t >= BATCH * PIX) return;
    int b = t / PIX, p = t % PIX;
    int row = p / H, col = p % H;
    int2 pk = pix[t];
    int fs = pk.x, fr = pk.y;
    float r, g, bc, a;
    if (fs < 0) {
        r = g = bc = 255.0f;
        a = 0.0f;
    } else {
        float px = axf(col), py = axf(row);
        float A[3];
        shade_face(fs, b, px, py, fd, verts, faces, vn, tm, A);
        r = A[0]; g = A[1]; bc = A[2];
        if (fr >= 0) {
            float Bc[3];
            shade_face(fr, b, px, py, fd, verts, faces, vn, tm, Bc);
            float As0 = bf16snap(A[0]), As1 = bf16snap(A[1]), As2 = bf16snap(A[2]);
            float Bs0 = bf16snap(Bc[0]), Bs1 = bf16snap(Bc[1]), Bs2 = bf16snap(Bc[2]);
            if (fabsf(As0 - Bs0) <= 9.01f && fabsf(As1 - Bs1) <= 9.01f &&
                fabsf(As2 - Bs2) <= 9.01f) {
                r  = 0.5f * (As0 + Bs0);
                g  = 0.5f * (As1 + Bs1);
                bc = 0.5f * (As2 + Bs2);
            }
        }
        a = 1.0f;
    }
    out[(((size_t)b*3 + 0) * H + row) * H + col] = r;
    out[(((size_t)b*3 + 1) * H + row) * H + col] = g;
    out[(((size_t)b*3 + 2) * H + row) * H + col] = bc;
    out[(size_t)BATCH*3*H*H + ((size_t)b * H + row) * H + col] = a;
}

extern "C" void kernel_launch(void* const* d_in, const int* in_sizes, int n_in,
                              void* d_out, int out_size, void* d_ws, size_t ws_size,
                              hipStream_t stream) {
    const float* verts = (const float*)d_in[0];
    const float* tm    = (const float*)d_in[1];
    const float* focal = (const float*)d_in[2];
    const int*   faces = (const int*)d_in[3];
    float* out = (float*)d_out;

    char* ws = (char*)d_ws;
    float* fd      = (float*)ws;                     // 1,276,928
    float* vn      = (float*)(ws + 1276928);         //   120,576 ┐
    int*   hist    = (int*)  (ws + 1397504);         //    32,768 ├ one memset (186,112 B)
    int*   cursor  = (int*)  (ws + 1430272);         //    32,768 ┘
    int2*  pix     = (int2*) (ws + 1463040);         // 1,048,576
    float* fds     = (float*)(ws + 2511616);         // 1,276,928
    float* blow    = (float*)(ws + 3788544);         //    79,872
    float* zminArr = (float*)(ws + 3868416);         //    79,872
    int*   start   = (int*)  (ws + 3948288);         //    32,768
    int*   total   = (int*)  (ws + 3981056);         //       256

    hipMemsetAsync(vn, 0, 186112, stream);           // vn + hist + cursor

    setup_all<<<(BATCH * NF + 255) / 256, 256, 0, stream>>>(verts, tm, focal, faces,
                                                            fd, zminArr, vn, hist);
    zscan<<<BATCH, 256, 0, stream>>>(hist, start, total);
    zscatter<<<(BATCH * NF + 255) / 256, 256, 0, stream>>>(fd, zminArr, start, cursor,
                                                           fds, blow, vn);
    dim3 rg(32, 32, BATCH);
    raster<<<rg, 64, 0, stream>>>(fds, blow, total, pix);

    shade<<<(BATCH * PIX + 255) / 256, 256, 0, stream>>>(pix, fd, verts, faces, vn, tm, out);
}

// Round 21
// 293.163 us; speedup vs baseline: 4.5236x; 1.0223x over previous
//
#include <hip/hip_runtime.h>
#include <stdint.h>

#define H 256
#define PIX (H*H)
#define BATCH 2
#define NV 5023
#define NF 9976
#define EPS 1e-5f
#define CH 128
#define NBUCK 4096

typedef unsigned long long ull;
#define INF_KEY 0x7F800000FFFFFFFFULL

__device__ __forceinline__ float axf(int i) {
    return 1.0f - (2.0f * (float)i + 1.0f) / (float)H;   // exact
}

__device__ __forceinline__ float bf16snap(float x) {     // round-to-nearest-even bf16
    unsigned u = __float_as_uint(x);
    unsigned r = (u + 0x7FFFu + ((u >> 16) & 1u)) & 0xFFFF0000u;
    return __uint_as_float(r);
}

__device__ __forceinline__ int zbucket(float z) {
    int q = (int)floorf((z - 0.5f) * (4096.0f / 3.0f));
    return q < 0 ? 0 : (q > 4095 ? 4095 : q);
}
__device__ __forceinline__ float zbucket_lower(int q) {
    return (q == 0) ? 0.0f : 0.5f + (float)q * (3.0f / 4096.0f);
}

// fused face setup (arithmetic byte-identical to r11-r20) + fn scatter + zhist
__global__ void setup_all(const float* __restrict__ verts, const float* __restrict__ tm,
                          const float* __restrict__ focal, const int* __restrict__ faces,
                          float* __restrict__ fd, float* __restrict__ zminArr,
                          float* __restrict__ vn, int* __restrict__ hist) {
#pragma clang fp contract(off)
    int t = blockIdx.x * blockDim.x + threadIdx.x;
    if (t >= BATCH * NF) return;
    int b = t / NF, f = t % NF;
    const float* M = tm + b * 12;
    float fl = focal[b];
    float X[3], Y[3], Z[3];
#pragma unroll
    for (int k = 0; k < 3; k++) {
        int vi = faces[f * 3 + k];
        const float* v = verts + (b * NV + vi) * 3;
        float v0 = v[0], v1 = v[1], v2 = v[2];
        float c0 = ((v0 * M[0] + v1 * M[4]) + v2 * M[8])  + M[3];
        float c1 = ((v0 * M[1] + v1 * M[5]) + v2 * M[9])  + M[7];
        float c2 = ((v0 * M[2] + v1 * M[6]) + v2 * M[10]) + M[11];
        X[k] = (fl * c0) / c2;
        Y[k] = (fl * c1) / c2;
        Z[k] = c2;
    }
    float x0 = X[0], x1 = X[1], x2 = X[2];
    float y0 = Y[0], y1 = Y[1], y2 = Y[2];
    float z0 = Z[0], z1 = Z[1], z2 = Z[2];
    float den = (y1 - y2) * (x0 - x2) + (x2 - x1) * (y0 - y2);
    bool zv = (z0 > EPS) && (z1 > EPS) && (z2 > EPS);
    bool okS = zv && (fabsf(den) > 1e-8f);
    bool okR = zv && (fabsf(den) > 5e-9f);
    float xmn, xmx, ymn, ymx;
    if (okR) {
        float e01 = (x1 - x0) * (x1 - x0) + (y1 - y0) * (y1 - y0);
        float e12 = (x2 - x1) * (x2 - x1) + (y2 - y1) * (y2 - y1);
        float e20 = (x0 - x2) * (x0 - x2) + (y0 - y2) * (y0 - y2);
        float E2 = fmaxf(fmaxf(e01, e12), e20);
        float delta = 1e-4f * E2 / fabsf(den) + 1e-3f;
        if (!(delta < 4.0f)) delta = 4.0f;
        xmn = fminf(fminf(x0, x1), x2) - delta;
        xmx = fmaxf(fmaxf(x0, x1), x2) + delta;
        ymn = fminf(fminf(y0, y1), y2) - delta;
        ymx = fmaxf(fmaxf(y0, y1), y2) + delta;
    } else {
        xmn = 1e30f; xmx = -1e30f; ymn = 1e30f; ymx = -1e30f;
    }
    float* o = fd + (size_t)t * 16;
    o[0] = y1 - y2;  o[1] = x2 - x1;
    o[2] = y2 - y0;  o[3] = x0 - x2;
    o[4] = x2;       o[5] = y2;
    o[6] = den;      o[7] = okS ? 1.0f : 0.0f;
    o[8] = xmn;  o[9] = xmx;  o[10] = ymn;  o[11] = ymx;
    o[12] = z0;  o[13] = z1;  o[14] = z2;   o[15] = 0.0f;
    float zm = okR ? fminf(fminf(z0, z1), z2) : -1.0f;
    zminArr[t] = zm;
    if (zm >= 0.0f) atomicAdd(&hist[b * NBUCK + zbucket(zm)], 1);

    // face-normal scatter (same math as r11-r20)
    {
        int i0 = faces[f*3+0], i1 = faces[f*3+1], i2 = faces[f*3+2];
        const float* vb = verts + b * NV * 3;
        float a0 = vb[i0*3+0], a1 = vb[i0*3+1], a2 = vb[i0*3+2];
        float b0 = vb[i1*3+0], b1 = vb[i1*3+1], b2 = vb[i1*3+2];
        float c0 = vb[i2*3+0], c1 = vb[i2*3+1], c2 = vb[i2*3+2];
        float e1x = b0 - a0, e1y = b1 - a1, e1z = b2 - a2;
        float e2x = c0 - a0, e2y = c1 - a1, e2z = c2 - a2;
        float nx = e1y * e2z - e1z * e2y;
        float ny = e1z * e2x - e1x * e2z;
        float nz = e1x * e2y - e1y * e2x;
        float* nb = vn + (size_t)b * NV * 3;
        atomicAdd(&nb[i0*3+0], nx); atomicAdd(&nb[i0*3+1], ny); atomicAdd(&nb[i0*3+2], nz);
        atomicAdd(&nb[i1*3+0], nx); atomicAdd(&nb[i1*3+1], ny); atomicAdd(&nb[i1*3+2], nz);
        atomicAdd(&nb[i2*3+0], nx); atomicAdd(&nb[i2*3+1], ny); atomicAdd(&nb[i2*3+2], nz);
    }
}

__global__ __launch_bounds__(256) void zscan(const int* __restrict__ hist,
                                             int* __restrict__ start,
                                             int* __restrict__ total) {
    int b = blockIdx.x;
    __shared__ int tot[256];
    int t = threadIdx.x;
    int a[16]; int s = 0;
#pragma unroll
    for (int i = 0; i < 16; i++) { int c = hist[b * NBUCK + t * 16 + i]; a[i] = s; s += c; }
    tot[t] = s;
    __syncthreads();
    for (int off = 1; off < 256; off <<= 1) {
        int x = tot[t];
        if (t >= off) x += tot[t - off];
        __syncthreads();
        tot[t] = x;
        __syncthreads();
    }
    int pre = (t > 0) ? tot[t - 1] : 0;
#pragma unroll
    for (int i = 0; i < 16; i++) start[b * NBUCK + t * 16 + i] = pre + a[i];
    if (t == 255) total[b] = tot[255];
}

// z-sort scatter + fused vertex-normal normalize
__global__ void zscatter(const float* __restrict__ fd, const float* __restrict__ zminArr,
                         const int* __restrict__ start, int* __restrict__ cursor,
                         float* __restrict__ fds, float* __restrict__ blow,
                         float* __restrict__ vn) {
#pragma clang fp contract(off)
    int t = blockIdx.x * blockDim.x + threadIdx.x;
    if (t < BATCH * NV) {
        float x = vn[t*3+0], y = vn[t*3+1], z = vn[t*3+2];
        float n = fmaxf(sqrtf((x*x + y*y) + z*z), 1e-6f);
        vn[t*3+0] = x / n; vn[t*3+1] = y / n; vn[t*3+2] = z / n;
    }
    if (t >= BATCH * NF) return;
    float zm = zminArr[t];
    if (zm < 0.0f) return;
    int b = t / NF, f = t % NF;
    int q = zbucket(zm);
    int dst = start[b * NBUCK + q] + atomicAdd(&cursor[b * NBUCK + q], 1);
    const float* o = fd + (size_t)t * 16;
    float* d = fds + ((size_t)b * NF + dst) * 16;
#pragma unroll
    for (int k = 0; k < 15; k++) d[k] = o[k];
    d[15] = __uint_as_float((unsigned)f);          // original face id
    blow[(size_t)b * NF + dst] = zbucket_lower(q); // certified lower bound
}

// 4-wave quadrant raster: waves split candidates mod 4 (disjoint faces);
// chunk-boundary break evaluated on the MERGED state (== single-scanner state
// at the same boundary -> identical break timing + final output, r12 proof).
// Per-face eval + pre-filter + selection keys byte-identical to r20.
__global__ __launch_bounds__(256) void raster(const float* __restrict__ fds,
                                              const float* __restrict__ blow,
                                              const int* __restrict__ total,
                                              int2* __restrict__ pix) {
#pragma clang fp contract(off)
    __shared__ __align__(16) float4 sbb[CH];
    __shared__ __align__(16) float sfd[CH * 16];
    __shared__ int slist[CH];
    __shared__ int scnt;
    __shared__ ull mks[4][64], mk1[4][64], mk2[4][64];
    int tid = threadIdx.x;
    int wid = tid >> 6, lane = tid & 63;
    int b = blockIdx.z;
    int id = blockIdx.y * 32 + blockIdx.x;
    int sw = (id * 733) & 1023;                    // CU swizzle (bijection)
    int col0 = (sw & 31) * 8, row0 = (sw >> 5) * 8;
    int col = col0 + (lane & 7), row = row0 + (lane >> 3);
    float px = axf(col), py = axf(row);
    float qxmax = axf(col0), qxmin = axf(col0 + 7);
    float qymax = axf(row0), qymin = axf(row0 + 7);
    ull ks = INF_KEY, k1 = INF_KEY, k2 = INF_KEY;  // per-wave per-lane
    const float4* fdb4 = (const float4*)(fds + (size_t)b * NF * 16);
    int cntb = total[b];

    for (int fbase = 0; fbase < cntb; fbase += CH) {
        int n = min(CH, cntb - fbase);
        if (tid == 0) scnt = 0;
        for (int j = tid; j < n; j += 256)
            sbb[j] = fdb4[(size_t)(fbase + j) * 4 + 2];
        __syncthreads();
        if (tid < n) {
            float4 bb = sbb[tid];
            if (bb.x <= qxmax && bb.y >= qxmin && bb.z <= qymax && bb.w >= qymin) {
                int p2 = atomicAdd(&scnt, 1);
                slist[p2] = tid;
            }
        }
        __syncthreads();
        int cnt = scnt;
        for (int j = tid; j < cnt * 4; j += 256) {
            int e = fbase + slist[j >> 2];
            ((float4*)sfd)[j] = fdb4[(size_t)e * 4 + (j & 3)];
        }
        __syncthreads();
        // candidate split: wave w evals i = w, w+4, ... (disjoint faces)
        for (int i = wid; i < cnt; i += 4) {
            const float* o = sfd + i * 16;
            bool cand = (px >= o[8]) & (px <= o[9]) & (py >= o[10]) & (py <= o[11]);
            if (__ballot(cand) == 0ULL) continue;
            float dx = px - o[4], dy = py - o[5];
            float num0 = o[0] * dx + o[1] * dy;
            float num1 = o[2] * dx + o[3] * dy;
            float adsn = fabsf(o[6]);
            float dsgn = (o[6] > 0.0f) ? 1.0f : -1.0f;
            float n0s = num0 * dsgn, n1s = num1 * dsgn;
            float thr = 2e-5f * adsn, thr2 = 1.001f * adsn;
            bool plaus = cand && (n0s >= -thr) && (n1s >= -thr) && ((n0s + n1s) <= thr2);
            if (__ballot(plaus) == 0ULL) continue;
            if (plaus) {
                float w0 = num0 / o[6];
                float w1 = num1 / o[6];
                float w2 = (1.0f - w0) - w1;
                bool insS = (o[7] != 0.0f) && (w0 >= 0.0f) && (w1 >= 0.0f) && (w2 >= 0.0f);
                bool insR = (w0 >= -1e-5f) && (w1 >= -1e-5f) && (w2 >= -1e-5f);
                if (insR) {
                    float iz = ((w0 / o[12]) + (w1 / o[13])) + (w2 / o[14]);
                    if (iz > 1e-8f) {
                        float zp = 1.0f / iz;
                        ull key = ((ull)__float_as_uint(zp) << 32) |
                                  (ull)(unsigned)__float_as_uint(o[15]);
                        if (insS && key < ks) ks = key;
                        if (key < k1) { k2 = k1; k1 = key; }
                        else if (key < k2) { k2 = key; }
                    }
                }
            }
        }
        // chunk-boundary break on MERGED state (frozen r18 inequality)
        if (fbase + CH < cntb) {
            mks[wid][lane] = ks; mk1[wid][lane] = k1; mk2[wid][lane] = k2;
            __syncthreads();
            ull Ks = mks[0][lane];
            if (mks[1][lane] < Ks) Ks = mks[1][lane];
            if (mks[2][lane] < Ks) Ks = mks[2][lane];
            if (mks[3][lane] < Ks) Ks = mks[3][lane];
            ull m1 = INF_KEY, m2 = INF_KEY;
#pragma unroll
            for (int w = 0; w < 4; w++) {
                ull v = mk1[w][lane];
                if (v < m1) { m2 = m1; m1 = v; } else if (v < m2 && v != m1) m2 = v;
                v = mk2[w][lane];
                if (v < m1) { m2 = m1; m1 = v; } else if (v < m2 && v != m1) m2 = v;
            }
            float nf = blow[(size_t)b * NF + fbase + CH];
            float madj = nf * (1.0f - 1e-4f);
            float zsv = __uint_as_float((unsigned)(Ks >> 32));
            float zbv = __uint_as_float((unsigned)(m2 >> 32));
            bool oldc = (Ks != INF_KEY) && (m2 != INF_KEY) && (zsv < madj) && (zbv < madj);
            bool newc = (Ks != INF_KEY) && (1.051f * zsv < madj);
            bool done = (nf > 0.0f) && (oldc || newc);
            int notdone = __syncthreads_count(done ? 0 : 1);
            if (notdone == 0) break;
        }
    }
    // final merge across waves + inline (fs, fr) merge (identical semantics)
    mks[wid][lane] = ks; mk1[wid][lane] = k1; mk2[wid][lane] = k2;
    __syncthreads();
    if (wid == 0) {
        ull Ks = mks[0][lane];
        if (mks[1][lane] < Ks) Ks = mks[1][lane];
        if (mks[2][lane] < Ks) Ks = mks[2][lane];
        if (mks[3][lane] < Ks) Ks = mks[3][lane];
        ull m1 = INF_KEY, m2 = INF_KEY;
#pragma unroll
        for (int w = 0; w < 4; w++) {
            ull v = mk1[w][lane];
            if (v < m1) { m2 = m1; m1 = v; } else if (v < m2 && v != m1) m2 = v;
            v = mk2[w][lane];
            if (v < m1) { m2 = m1; m1 = v; } else if (v < m2 && v != m1) m2 = v;
        }
        int fs = -1;
        float zs = 0.0f;
        if ((unsigned)(Ks >> 32) != 0x7F800000u) {
            fs = (int)(unsigned)Ks;
            zs = __uint_as_float((unsigned)(Ks >> 32));
        }
        int fr = -1;
        if (fs >= 0) {
            ull mR = INF_KEY;
            if ((int)(unsigned)m1 != fs && m1 < mR) mR = m1;
            if ((int)(unsigned)m2 != fs && m2 < mR) mR = m2;
            if ((unsigned)(mR >> 32) != 0x7F800000u) {
                float zr = __uint_as_float((unsigned)(mR >> 32));
                if (fabsf(zr - zs) <= 0.05f * zs) fr = (int)(unsigned)mR;
            }
        }
        pix[(size_t)b * PIX + (size_t)row * H + col] = make_int2(fs, fr);
    }
}

// faithful f32 shading (identical values to r11-r20)
__device__ void shade_face(int f, int b, float px, float py,
                           const float* __restrict__ fd, const float* __restrict__ verts,
                           const int* __restrict__ faces, const float* __restrict__ vn,
                           const float* __restrict__ tm, float* rgb) {
#pragma clang fp contract(off)
    const float* o = fd + ((size_t)b * NF + f) * 16;
    float dx = px - o[4], dy = py - o[5];
    float w0 = (o[0] * dx + o[1] * dy) / o[6];
    float w1 = (o[2] * dx + o[3] * dy) / o[6];
    float w2 = (1.0f - w0) - w1;
    float q0 = w0 / o[12], q1 = w1 / o[13], q2 = w2 / o[14];
    float iz = (q0 + q1) + q2;
    float zsafe = 1.0f / iz;
    float bw0 = q0 * zsafe, bw1 = q1 * zsafe, bw2 = q2 * zsafe;
    int i0 = faces[f*3+0], i1 = faces[f*3+1], i2 = faces[f*3+2];
    const float* vb = verts + b * NV * 3;
    const float* nb = vn + b * NV * 3;
    float posx = (bw0*vb[i0*3+0] + bw1*vb[i1*3+0]) + bw2*vb[i2*3+0];
    float posy = (bw0*vb[i0*3+1] + bw1*vb[i1*3+1]) + bw2*vb[i2*3+1];
    float posz = (bw0*vb[i0*3+2] + bw1*vb[i1*3+2]) + bw2*vb[i2*3+2];
    float nx = (bw0*nb[i0*3+0] + bw1*nb[i1*3+0]) + bw2*nb[i2*3+0];
    float ny = (bw0*nb[i0*3+1] + bw1*nb[i1*3+1]) + bw2*nb[i2*3+1];
    float nz = (bw0*nb[i0*3+2] + bw1*nb[i1*3+2]) + bw2*nb[i2*3+2];
    float nn = fmaxf(sqrtf((nx*nx + ny*ny) + nz*nz), 1e-6f);
    nx /= nn; ny /= nn; nz /= nn;
    const float* M = tm + b * 12;
    float T0 = M[3], T1 = M[7], T2 = M[11];
    float cpx = -((T0*M[0] + T1*M[1]) + T2*M[2]);
    float cpy = -((T0*M[4] + T1*M[5]) + T2*M[6]);
    float cpz = -((T0*M[8] + T1*M[9]) + T2*M[10]);
    float lx = 0.0f - posx, ly = 1.0f - posy, lz = 3.0f - posz;
    float ln = fmaxf(sqrtf((lx*lx + ly*ly) + lz*lz), 1e-6f);
    lx /= ln; ly /= ln; lz /= ln;
    float vx = cpx - posx, vy = cpy - posy, vz = cpz - posz;
    float vnn = fmaxf(sqrtf((vx*vx + vy*vy) + vz*vz), 1e-6f);
    vx /= vnn; vy /= vnn; vz /= vnn;
    float cosNL = (nx*lx + ny*ly) + nz*lz;
    float diffuse = 0.3f * fmaxf(cosNL, 0.0f);
    float rx = (2.0f * cosNL) * nx - lx;
    float ry = (2.0f * cosNL) * ny - ly;
    float rz = (2.0f * cosNL) * nz - lz;
    float vr = (vx*rx + vy*ry) + vz*rz;
    float spec = 0.12f * powf(fmaxf(vr, 0.0f), 10.0f);
    float sA = 0.5f + diffuse;
    rgb[0] = ((142.0f / 255.0f) * sA + spec) * 255.0f;
    rgb[1] = ((179.0f / 255.0f) * sA + spec) * 255.0f;
    rgb[2] = ((247.0f / 255.0f) * sA + spec) * 255.0f;
}

__global__ void shade(const int2* __restrict__ pix, const float* __restrict__ fd,
                      const float* __restrict__ verts, const int* __restrict__ faces,
                      const float* __restrict__ vn, const float* __restrict__ tm,
                      float* __restrict__ out) {
#pragma clang fp contract(off)
    int t = blockIdx.x * blockDim.x + threadIdx.x;
    if (t >= BATCH * PIX) return;
    int b = t / PIX, p = t % PIX;
    int row = p / H, col = p % H;
    int2 pk = pix[t];
    int fs = pk.x, fr = pk.y;
    float r, g, bc, a;
    if (fs < 0) {
        r = g = bc = 255.0f;
        a = 0.0f;
    } else {
        float px = axf(col), py = axf(row);
        float A[3];
        shade_face(fs, b, px, py, fd, verts, faces, vn, tm, A);
        r = A[0]; g = A[1]; bc = A[2];
        if (fr >= 0) {
            float Bc[3];
            shade_face(fr, b, px, py, fd, verts, faces, vn, tm, Bc);
            float As0 = bf16snap(A[0]), As1 = bf16snap(A[1]), As2 = bf16snap(A[2]);
            float Bs0 = bf16snap(Bc[0]), Bs1 = bf16snap(Bc[1]), Bs2 = bf16snap(Bc[2]);
            if (fabsf(As0 - Bs0) <= 9.01f && fabsf(As1 - Bs1) <= 9.01f &&
                fabsf(As2 - Bs2) <= 9.01f) {
                r  = 0.5f * (As0 + Bs0);
                g  = 0.5f * (As1 + Bs1);
                bc = 0.5f * (As2 + Bs2);
            }
        }
        a = 1.0f;
    }
    out[(((size_t)b*3 + 0) * H + row) * H + col] = r;
    out[(((size_t)b*3 + 1) * H + row) * H + col] = g;
    out[(((size_t)b*3 + 2) * H + row) * H + col] = bc;
    out[(size_t)BATCH*3*H*H + ((size_t)b * H + row) * H + col] = a;
}

extern "C" void kernel_launch(void* const* d_in, const int* in_sizes, int n_in,
                              void* d_out, int out_size, void* d_ws, size_t ws_size,
                              hipStream_t stream) {
    const float* verts = (const float*)d_in[0];
    const float* tm    = (const float*)d_in[1];
    const float* focal = (const float*)d_in[2];
    const int*   faces = (const int*)d_in[3];
    float* out = (float*)d_out;

    char* ws = (char*)d_ws;
    float* fd      = (float*)ws;                     // 1,276,928
    float* vn      = (float*)(ws + 1276928);         //   120,576 ┐
    int*   hist    = (int*)  (ws + 1397504);         //    32,768 ├ one memset (186,112 B)
    int*   cursor  = (int*)  (ws + 1430272);         //    32,768 ┘
    int2*  pix     = (int2*) (ws + 1463040);         // 1,048,576
    float* fds     = (float*)(ws + 2511616);         // 1,276,928
    float* blow    = (float*)(ws + 3788544);         //    79,872
    float* zminArr = (float*)(ws + 3868416);         //    79,872
    int*   start   = (int*)  (ws + 3948288);         //    32,768
    int*   total   = (int*)  (ws + 3981056);         //       256

    hipMemsetAsync(vn, 0, 186112, stream);           // vn + hist + cursor

    setup_all<<<(BATCH * NF + 255) / 256, 256, 0, stream>>>(verts, tm, focal, faces,
                                                            fd, zminArr, vn, hist);
    zscan<<<BATCH, 256, 0, stream>>>(hist, start, total);
    zscatter<<<(BATCH * NF + 255) / 256, 256, 0, stream>>>(fd, zminArr, start, cursor,
                                                           fds, blow, vn);
    dim3 rg(32, 32, BATCH);
    raster<<<rg, 256, 0, stream>>>(fds, blow, total, pix);

    shade<<<(BATCH * PIX + 255) / 256, 256, 0, stream>>>(pix, fd, verts, faces, vn, tm, out);
}